// Round 1
// baseline (1031.362 us; speedup 1.0000x reference)
//
#include <hip/hip_runtime.h>
#include <math.h>

#define NN 50000
#define NE 800000

__device__ __forceinline__ float leaky(float x){ return x > 0.f ? x : 0.2f*x; }

// ---------------- CSR build ----------------
__global__ void k_hist(const int* __restrict__ col, int* __restrict__ deg){
  int e = blockIdx.x*blockDim.x + threadIdx.x;
  if (e < NE) atomicAdd(&deg[col[e]], 1);
}

__global__ void k_scan(const int* __restrict__ deg, int* __restrict__ off, int* __restrict__ cursor){
  __shared__ int buf[1024];
  __shared__ int carry_s;
  if (threadIdx.x==0) carry_s = 0;
  __syncthreads();
  for (int base=0; base<NN; base+=1024){
    int i = base + (int)threadIdx.x;
    int v = (i<NN)? deg[i] : 0;
    buf[threadIdx.x] = v;
    __syncthreads();
    for (int s=1;s<1024;s<<=1){
      int t = (threadIdx.x >= (unsigned)s)? buf[threadIdx.x-s] : 0;
      __syncthreads();
      buf[threadIdx.x] += t;
      __syncthreads();
    }
    int excl = carry_s + buf[threadIdx.x] - v;
    if (i<NN){ off[i]=excl; cursor[i]=excl; }
    __syncthreads();
    if (threadIdx.x==1023) carry_s += buf[1023];
    __syncthreads();
  }
  if (threadIdx.x==0) off[NN]=carry_s;
}

__global__ void k_scatter(const int* __restrict__ row, const int* __restrict__ col,
                          int* __restrict__ cursor, int* __restrict__ esrc, int* __restrict__ eid){
  int e = blockIdx.x*blockDim.x + threadIdx.x;
  if (e < NE){
    int c = col[e];
    int pos = atomicAdd(&cursor[c], 1);
    esrc[pos] = row[e];
    eid[pos]  = e;
  }
}

// ---------------- scatter-mean of edge embeds onto nodes ----------------
__global__ void k_premix(const float* __restrict__ node, const float* __restrict__ ee,
                         const int* __restrict__ off, const int* __restrict__ eid,
                         float* __restrict__ X){
  int wid  = (int)((blockIdx.x*blockDim.x + threadIdx.x) >> 6);
  int lane = threadIdx.x & 63;
  if (wid >= NN) return;
  int s0 = off[wid], s1 = off[wid+1];
  float acc = 0.f;
  for (int p=s0; p<s1; ++p){
    int ed = eid[p];
    acc += ee[(size_t)ed*64 + lane];
  }
  float c = (float)((s1-s0) > 1 ? (s1-s0) : 1);
  X[(size_t)wid*64 + lane] = node[(size_t)wid*64 + lane] + acc / c;
}

// ---------------- f32 tiled GEMM: C[M,Nc] = A[M,K] * B[K,Nc] ----------------
// K % 16 == 0, Nc % 64 == 0
__global__ void k_gemm(const float* __restrict__ A, const float* __restrict__ B,
                       float* __restrict__ C, int M, int K, int Nc){
  __shared__ float As[16][65];
  __shared__ float Bs[16][65];
  int bm = blockIdx.y * 64, bn = blockIdx.x * 64;
  int tid = threadIdx.x;
  int tr = tid >> 4, tc = tid & 15;      // 16x16 thread grid, each 4x4 outputs
  int lm = tid & 63, lk = tid >> 6;      // loader mapping
  float acc[4][4];
  #pragma unroll
  for (int i=0;i<4;++i)
    #pragma unroll
    for (int j=0;j<4;++j) acc[i][j]=0.f;

  for (int k0=0; k0<K; k0+=16){
    #pragma unroll
    for (int kk=0; kk<4; ++kk){
      int m = bm + lm, k = k0 + lk*4 + kk;
      As[lk*4+kk][lm] = (m < M) ? A[(size_t)m*K + k] : 0.f;
      Bs[lk*4+kk][lm] = B[(size_t)k*Nc + bn + lm];
    }
    __syncthreads();
    #pragma unroll
    for (int kk=0; kk<16; ++kk){
      float a[4], b[4];
      #pragma unroll
      for (int i=0;i<4;++i) a[i] = As[kk][tr*4+i];
      #pragma unroll
      for (int j=0;j<4;++j) b[j] = Bs[kk][tc*4+j];
      #pragma unroll
      for (int i=0;i<4;++i)
        #pragma unroll
        for (int j=0;j<4;++j) acc[i][j] += a[i]*b[j];
    }
    __syncthreads();
  }
  #pragma unroll
  for (int i=0;i<4;++i){
    int m = bm + tr*4 + i;
    if (m < M){
      #pragma unroll
      for (int j=0;j<4;++j) C[(size_t)m*Nc + bn + tc*4 + j] = acc[i][j];
    }
  }
}

// ---------------- per-node attention coefficients a_s, a_d ----------------
template<int HEADS>
__global__ void k_coef(const float* __restrict__ Hb, const float* __restrict__ asrc,
                       const float* __restrict__ adst,
                       float* __restrict__ AS, float* __restrict__ AD){
  constexpr int D   = HEADS*64;
  constexpr int VPL = D/64;
  constexpr int G   = 64/HEADS;
  int wid  = (int)((blockIdx.x*blockDim.x + threadIdx.x) >> 6);
  int lane = threadIdx.x & 63;
  if (wid >= NN) return;
  float s_=0.f, d_=0.f;
  #pragma unroll
  for (int v=0; v<VPL; ++v){
    int idx = lane*VPL + v;
    float h = Hb[(size_t)wid*D + idx];
    s_ += h * asrc[idx];
    d_ += h * adst[idx];
  }
  #pragma unroll
  for (int mk=1; mk<G; mk<<=1){
    s_ += __shfl_xor(s_, mk, 64);
    d_ += __shfl_xor(d_, mk, 64);
  }
  if ((lane & (G-1)) == 0){
    int head = lane / G;
    AS[(size_t)wid*HEADS + head] = s_;
    AD[(size_t)wid*HEADS + head] = d_;
  }
}

// ---------------- per-node segment-softmax aggregation + bias + LN + ELU ----------------
template<int HEADS>
__global__ void k_agg(const float* __restrict__ Hb, const float* __restrict__ AS,
                      const float* __restrict__ AD, const int* __restrict__ off,
                      const int* __restrict__ esrc,
                      const float* __restrict__ bias, const float* __restrict__ gamma,
                      const float* __restrict__ beta, float* __restrict__ Out){
  constexpr int D   = HEADS*64;
  constexpr int VPL = D/64;
  int wid  = (int)((blockIdx.x*blockDim.x + threadIdx.x) >> 6);
  int lane = threadIdx.x & 63;
  if (wid >= NN) return;
  int head = (lane*VPL) >> 6;
  float ad = AD[(size_t)wid*HEADS + head];
  float wself = leaky(AS[(size_t)wid*HEADS + head] + ad);
  int s0 = off[wid], s1 = off[wid+1];

  // pass 1: segment max (incl. self-loop)
  float m = wself;
  for (int p=s0; p<s1; ++p){
    int src = esrc[p];
    m = fmaxf(m, leaky(AS[(size_t)src*HEADS + head] + ad));
  }

  // pass 2: weighted accumulate
  float acc[VPL];
  #pragma unroll
  for (int v=0;v<VPL;++v) acc[v]=0.f;
  float psum = 0.f;
  for (int p=s0; p<s1; ++p){
    int src = esrc[p];
    float pw = expf(leaky(AS[(size_t)src*HEADS + head] + ad) - m);
    psum += pw;
    if constexpr (VPL==4){
      float4 hv = *reinterpret_cast<const float4*>(Hb + (size_t)src*D + lane*4);
      acc[0] += pw*hv.x; acc[1] += pw*hv.y; acc[2] += pw*hv.z; acc[3] += pw*hv.w;
    } else {
      acc[0] += pw * Hb[(size_t)src*D + lane];
    }
  }
  { // self loop
    float pw = expf(wself - m);
    psum += pw;
    if constexpr (VPL==4){
      float4 hv = *reinterpret_cast<const float4*>(Hb + (size_t)wid*D + lane*4);
      acc[0] += pw*hv.x; acc[1] += pw*hv.y; acc[2] += pw*hv.z; acc[3] += pw*hv.w;
    } else {
      acc[0] += pw * Hb[(size_t)wid*D + lane];
    }
  }

  float inv = 1.f/psum;
  float val[VPL];
  float s=0.f, s2=0.f;
  #pragma unroll
  for (int v=0;v<VPL;++v){
    val[v] = acc[v]*inv + bias[lane*VPL+v];
    s  += val[v];
    s2 += val[v]*val[v];
  }
  #pragma unroll
  for (int mk=1; mk<64; mk<<=1){
    s  += __shfl_xor(s,  mk, 64);
    s2 += __shfl_xor(s2, mk, 64);
  }
  float mean = s/(float)D;
  float var  = s2/(float)D - mean*mean;
  float rstd = rsqrtf(var + 1e-5f);
  #pragma unroll
  for (int v=0;v<VPL;++v){
    float y = (val[v]-mean)*rstd*gamma[lane*VPL+v] + beta[lane*VPL+v];
    Out[(size_t)wid*D + lane*VPL+v] = (y > 0.f) ? y : expm1f(y);
  }
}

// ---------------- launcher ----------------
extern "C" void kernel_launch(void* const* d_in, const int* in_sizes, int n_in,
                              void* d_out, int out_size, void* d_ws, size_t ws_size,
                              hipStream_t stream) {
  const float* node  = (const float*)d_in[0];
  const int*   eidx  = (const int*)d_in[1];
  const float* ee    = (const float*)d_in[2];
  const float* W0    = (const float*)d_in[3];
  const float* asrc0 = (const float*)d_in[4];
  const float* adst0 = (const float*)d_in[5];
  const float* b0    = (const float*)d_in[6];
  const float* g0    = (const float*)d_in[7];
  const float* be0   = (const float*)d_in[8];
  const float* W1    = (const float*)d_in[9];
  const float* asrc1 = (const float*)d_in[10];
  const float* adst1 = (const float*)d_in[11];
  const float* b1    = (const float*)d_in[12];
  const float* g1    = (const float*)d_in[13];
  const float* be1   = (const float*)d_in[14];
  const float* W2    = (const float*)d_in[15];
  const float* asrc2 = (const float*)d_in[16];
  const float* adst2 = (const float*)d_in[17];
  const float* b2    = (const float*)d_in[18];
  const float* g2    = (const float*)d_in[19];
  const float* be2   = (const float*)d_in[20];

  const int* row = eidx;
  const int* col = eidx + NE;

  float* X   = (float*)d_ws;            // [NN,256] (layer0 uses [NN,64])
  float* Hb  = X  + (size_t)NN*256;     // [NN,256]
  float* AS  = Hb + (size_t)NN*256;     // [NN,4]
  float* AD  = AS + (size_t)NN*4;       // [NN,4]
  int* deg   = (int*)(AD + (size_t)NN*4);
  int* off   = deg + NN;                // NN+1
  int* cursor= off + NN + 1;
  int* esrc  = cursor + NN;             // NE
  int* eid   = esrc + NE;               // NE

  float* out = (float*)d_out;

  // CSR build
  hipMemsetAsync(deg, 0, NN*sizeof(int), stream);
  k_hist<<<(NE+255)/256, 256, 0, stream>>>(col, deg);
  k_scan<<<1, 1024, 0, stream>>>(deg, off, cursor);
  k_scatter<<<(NE+255)/256, 256, 0, stream>>>(row, col, cursor, esrc, eid);

  // x = node + scatter_mean(edge_embeds)
  int nwaveblk = (NN*64 + 255)/256;
  k_premix<<<nwaveblk, 256, 0, stream>>>(node, ee, off, eid, X);

  // ---- layer 0: din=64, heads=4, dout=256 ----
  {
    dim3 g(256/64, (NN+63)/64);
    k_gemm<<<g, 256, 0, stream>>>(X, W0, Hb, NN, 64, 256);
    k_coef<4><<<nwaveblk, 256, 0, stream>>>(Hb, asrc0, adst0, AS, AD);
    k_agg<4><<<nwaveblk, 256, 0, stream>>>(Hb, AS, AD, off, esrc, b0, g0, be0, X);
  }
  // ---- layer 1: din=256, heads=4, dout=256 ----
  {
    dim3 g(256/64, (NN+63)/64);
    k_gemm<<<g, 256, 0, stream>>>(X, W1, Hb, NN, 256, 256);
    k_coef<4><<<nwaveblk, 256, 0, stream>>>(Hb, asrc1, adst1, AS, AD);
    k_agg<4><<<nwaveblk, 256, 0, stream>>>(Hb, AS, AD, off, esrc, b1, g1, be1, X);
  }
  // ---- layer 2: din=256, heads=1, dout=64, concat=False (mean of 1 head = identity) ----
  {
    dim3 g(64/64, (NN+63)/64);
    k_gemm<<<g, 256, 0, stream>>>(X, W2, Hb, NN, 256, 64);
    k_coef<1><<<nwaveblk, 256, 0, stream>>>(Hb, asrc2, adst2, AS, AD);
    k_agg<1><<<nwaveblk, 256, 0, stream>>>(Hb, AS, AD, off, esrc, b2, g2, be2, out);
  }
}

// Round 2
// 822.606 us; speedup vs baseline: 1.2538x; 1.2538x over previous
//
#include <hip/hip_runtime.h>
#include <math.h>

#define NN 50000
#define NE 800000
#define MPAD 50048   // 391 * 128

typedef __attribute__((ext_vector_type(8))) short bf16x8;
typedef __attribute__((ext_vector_type(4))) float f32x4;

__device__ __forceinline__ float leaky(float x){ return x > 0.f ? x : 0.2f*x; }

__device__ __forceinline__ unsigned short f2bf(float f){
  unsigned int u = __float_as_uint(f);
  unsigned int r = (u + 0x7fffu + ((u >> 16) & 1u)) >> 16;
  return (unsigned short)r;
}

// ---------------- CSR build ----------------
__global__ void k_hist(const int* __restrict__ col, int* __restrict__ deg){
  int e = blockIdx.x*blockDim.x + threadIdx.x;
  if (e < NE) atomicAdd(&deg[col[e]], 1);
}

__global__ void k_scan(const int* __restrict__ deg, int* __restrict__ off, int* __restrict__ cursor){
  __shared__ int buf[1024];
  __shared__ int carry_s;
  if (threadIdx.x==0) carry_s = 0;
  __syncthreads();
  for (int base=0; base<NN; base+=1024){
    int i = base + (int)threadIdx.x;
    int v = (i<NN)? deg[i] : 0;
    buf[threadIdx.x] = v;
    __syncthreads();
    for (int s=1;s<1024;s<<=1){
      int t = (threadIdx.x >= (unsigned)s)? buf[threadIdx.x-s] : 0;
      __syncthreads();
      buf[threadIdx.x] += t;
      __syncthreads();
    }
    int excl = carry_s + buf[threadIdx.x] - v;
    if (i<NN){ off[i]=excl; cursor[i]=excl; }
    __syncthreads();
    if (threadIdx.x==1023) carry_s += buf[1023];
    __syncthreads();
  }
  if (threadIdx.x==0) off[NN]=carry_s;
}

__global__ void k_scatter(const int* __restrict__ row, const int* __restrict__ col,
                          int* __restrict__ cursor, int* __restrict__ esrc, int* __restrict__ eid){
  int e = blockIdx.x*blockDim.x + threadIdx.x;
  if (e < NE){
    int c = col[e];
    int pos = atomicAdd(&cursor[c], 1);
    esrc[pos] = row[e];
    eid[pos]  = e;
  }
}

// ---------------- scatter-mean of edge embeds onto nodes (bf16 out) ----------------
__global__ void k_premix(const float* __restrict__ node, const float* __restrict__ ee,
                         const int* __restrict__ off, const int* __restrict__ eid,
                         unsigned short* __restrict__ Xb){
  int wid  = (int)((blockIdx.x*blockDim.x + threadIdx.x) >> 6);
  int lane = threadIdx.x & 63;
  if (wid >= NN) return;
  int s0 = off[wid], s1 = off[wid+1];
  float acc = 0.f;
  for (int p=s0; p<s1; ++p){
    int ed = eid[p];
    acc += ee[(size_t)ed*64 + lane];
  }
  float c = (float)((s1-s0) > 1 ? (s1-s0) : 1);
  Xb[(size_t)wid*64 + lane] = f2bf(node[(size_t)wid*64 + lane] + acc / c);
}

// ---------------- W convert+transpose: Wt[n][k] bf16 from W[k][n] f32 ----------------
__global__ void k_wconv(const float* __restrict__ W, unsigned short* __restrict__ Wt,
                        int K, int Ncols){
  int idx = blockIdx.x*blockDim.x + threadIdx.x;
  if (idx < K*Ncols){
    int n = idx / K, k = idx - n*K;
    Wt[idx] = f2bf(W[(size_t)k*Ncols + n]);
  }
}

// ---------------- bf16 MFMA GEMM: C[M,Nc] = A[M,K] * Bt[Nc,K]^T ----------------
// BM=128, BK=32, 4 waves in 2x2. A padded to MPAD rows; no bounds checks.
template<int BN, int K>
__global__ __launch_bounds__(256)
void k_gemm_mfma(const unsigned short* __restrict__ A,
                 const unsigned short* __restrict__ Bt,
                 float* __restrict__ C, int Nc){
  constexpr int BM = 128, BK = 32;
  constexpr int WNT = BN/32;            // 16-col frags per wave (2x2 waves)
  __shared__ __align__(16) unsigned short As[BM*BK];
  __shared__ __align__(16) unsigned short Bs[BN*BK];
  const int tid  = threadIdx.x;
  const int lane = tid & 63;
  const int wid  = tid >> 6;
  const int wr   = wid >> 1, wc = wid & 1;
  const int bm   = blockIdx.y * BM, bn = blockIdx.x * BN;
  const int r    = lane >> 2, kq = lane & 3;   // staging: 4 lanes per 64B row

  f32x4 acc[4][WNT];
  #pragma unroll
  for (int i=0;i<4;++i)
    #pragma unroll
    for (int j=0;j<WNT;++j) acc[i][j] = (f32x4){0.f,0.f,0.f,0.f};

  for (int k0=0; k0<K; k0+=BK){
    // stage A tile: 128 rows x 64B, wave w rows [w*32, w*32+32)
    #pragma unroll
    for (int i=0;i<2;++i){
      int arow = wid*32 + i*16 + r;
      __builtin_amdgcn_global_load_lds(
        (const __attribute__((address_space(1))) void*)(A + (size_t)(bm+arow)*K + k0 + kq*8),
        (__attribute__((address_space(3))) void*)&As[(wid*32 + i*16)*BK],
        16, 0, 0);
    }
    // stage B tile: BN rows x 64B
    #pragma unroll
    for (int i=0;i<BN/64;++i){
      int brow = wid*(BN/4) + i*16 + r;
      __builtin_amdgcn_global_load_lds(
        (const __attribute__((address_space(1))) void*)(Bt + (size_t)(bn+brow)*K + k0 + kq*8),
        (__attribute__((address_space(3))) void*)&Bs[(wid*(BN/4) + i*16)*BK],
        16, 0, 0);
    }
    __syncthreads();

    bf16x8 af[4], bfr[WNT];
    #pragma unroll
    for (int mi=0; mi<4; ++mi)
      af[mi] = *reinterpret_cast<const bf16x8*>(&As[(wr*64 + mi*16 + (lane&15))*BK + (lane>>4)*8]);
    #pragma unroll
    for (int ni=0; ni<WNT; ++ni)
      bfr[ni] = *reinterpret_cast<const bf16x8*>(&Bs[(wc*(BN/2) + ni*16 + (lane&15))*BK + (lane>>4)*8]);
    #pragma unroll
    for (int mi=0; mi<4; ++mi)
      #pragma unroll
      for (int ni=0; ni<WNT; ++ni)
        acc[mi][ni] = __builtin_amdgcn_mfma_f32_16x16x32_bf16(af[mi], bfr[ni], acc[mi][ni], 0, 0, 0);
    __syncthreads();
  }

  // epilogue: C[row][col], row=(lane>>4)*4+reg, col=lane&15 within each 16x16 frag
  #pragma unroll
  for (int mi=0; mi<4; ++mi){
    #pragma unroll
    for (int ni=0; ni<WNT; ++ni){
      int ccol = bn + wc*(BN/2) + ni*16 + (lane&15);
      int rbase = bm + wr*64 + mi*16 + (lane>>4)*4;
      #pragma unroll
      for (int reg=0; reg<4; ++reg)
        C[(size_t)(rbase+reg)*Nc + ccol] = acc[mi][ni][reg];
    }
  }
}

// ---------------- per-node attention coefficients a_s, a_d ----------------
template<int HEADS>
__global__ void k_coef(const float* __restrict__ Hb, const float* __restrict__ asrc,
                       const float* __restrict__ adst,
                       float* __restrict__ AS, float* __restrict__ AD){
  constexpr int D   = HEADS*64;
  constexpr int VPL = D/64;
  constexpr int G   = 64/HEADS;
  int wid  = (int)((blockIdx.x*blockDim.x + threadIdx.x) >> 6);
  int lane = threadIdx.x & 63;
  if (wid >= NN) return;
  float s_=0.f, d_=0.f;
  #pragma unroll
  for (int v=0; v<VPL; ++v){
    int idx = lane*VPL + v;
    float h = Hb[(size_t)wid*D + idx];
    s_ += h * asrc[idx];
    d_ += h * adst[idx];
  }
  #pragma unroll
  for (int mk=1; mk<G; mk<<=1){
    s_ += __shfl_xor(s_, mk, 64);
    d_ += __shfl_xor(d_, mk, 64);
  }
  if ((lane & (G-1)) == 0){
    int head = lane / G;
    AS[(size_t)wid*HEADS + head] = s_;
    AD[(size_t)wid*HEADS + head] = d_;
  }
}

// ---------------- per-node segment-softmax aggregation + bias + LN + ELU ----------------
template<int HEADS, bool OUT_BF16>
__global__ void k_agg(const float* __restrict__ Hb, const float* __restrict__ AS,
                      const float* __restrict__ AD, const int* __restrict__ off,
                      const int* __restrict__ esrc,
                      const float* __restrict__ bias, const float* __restrict__ gamma,
                      const float* __restrict__ beta, void* __restrict__ OutP){
  constexpr int D   = HEADS*64;
  constexpr int VPL = D/64;
  int wid  = (int)((blockIdx.x*blockDim.x + threadIdx.x) >> 6);
  int lane = threadIdx.x & 63;
  if (wid >= NN) return;
  int head = (lane*VPL) >> 6;
  float ad = AD[(size_t)wid*HEADS + head];
  float wself = leaky(AS[(size_t)wid*HEADS + head] + ad);
  int s0 = off[wid], s1 = off[wid+1];

  // pass 1: segment max (incl. self-loop)
  float m = wself;
  for (int p=s0; p<s1; ++p){
    int src = esrc[p];
    m = fmaxf(m, leaky(AS[(size_t)src*HEADS + head] + ad));
  }

  // pass 2: weighted accumulate
  float acc[VPL];
  #pragma unroll
  for (int v=0;v<VPL;++v) acc[v]=0.f;
  float psum = 0.f;
  for (int p=s0; p<s1; ++p){
    int src = esrc[p];
    float pw = expf(leaky(AS[(size_t)src*HEADS + head] + ad) - m);
    psum += pw;
    if constexpr (VPL==4){
      float4 hv = *reinterpret_cast<const float4*>(Hb + (size_t)src*D + lane*4);
      acc[0] += pw*hv.x; acc[1] += pw*hv.y; acc[2] += pw*hv.z; acc[3] += pw*hv.w;
    } else {
      acc[0] += pw * Hb[(size_t)src*D + lane];
    }
  }
  { // self loop
    float pw = expf(wself - m);
    psum += pw;
    if constexpr (VPL==4){
      float4 hv = *reinterpret_cast<const float4*>(Hb + (size_t)wid*D + lane*4);
      acc[0] += pw*hv.x; acc[1] += pw*hv.y; acc[2] += pw*hv.z; acc[3] += pw*hv.w;
    } else {
      acc[0] += pw * Hb[(size_t)wid*D + lane];
    }
  }

  float inv = 1.f/psum;
  float val[VPL];
  float s=0.f, s2=0.f;
  #pragma unroll
  for (int v=0;v<VPL;++v){
    val[v] = acc[v]*inv + bias[lane*VPL+v];
    s  += val[v];
    s2 += val[v]*val[v];
  }
  #pragma unroll
  for (int mk=1; mk<64; mk<<=1){
    s  += __shfl_xor(s,  mk, 64);
    s2 += __shfl_xor(s2, mk, 64);
  }
  float mean = s/(float)D;
  float var  = s2/(float)D - mean*mean;
  float rstd = rsqrtf(var + 1e-5f);
  #pragma unroll
  for (int v=0;v<VPL;++v){
    float y = (val[v]-mean)*rstd*gamma[lane*VPL+v] + beta[lane*VPL+v];
    y = (y > 0.f) ? y : expm1f(y);
    if constexpr (OUT_BF16)
      ((unsigned short*)OutP)[(size_t)wid*D + lane*VPL+v] = f2bf(y);
    else
      ((float*)OutP)[(size_t)wid*D + lane*VPL+v] = y;
  }
}

// ---------------- launcher ----------------
extern "C" void kernel_launch(void* const* d_in, const int* in_sizes, int n_in,
                              void* d_out, int out_size, void* d_ws, size_t ws_size,
                              hipStream_t stream) {
  const float* node  = (const float*)d_in[0];
  const int*   eidx  = (const int*)d_in[1];
  const float* ee    = (const float*)d_in[2];
  const float* W0    = (const float*)d_in[3];
  const float* asrc0 = (const float*)d_in[4];
  const float* adst0 = (const float*)d_in[5];
  const float* b0    = (const float*)d_in[6];
  const float* g0    = (const float*)d_in[7];
  const float* be0   = (const float*)d_in[8];
  const float* W1    = (const float*)d_in[9];
  const float* asrc1 = (const float*)d_in[10];
  const float* adst1 = (const float*)d_in[11];
  const float* b1    = (const float*)d_in[12];
  const float* g1    = (const float*)d_in[13];
  const float* be1   = (const float*)d_in[14];
  const float* W2    = (const float*)d_in[15];
  const float* asrc2 = (const float*)d_in[16];
  const float* adst2 = (const float*)d_in[17];
  const float* b2    = (const float*)d_in[18];
  const float* g2    = (const float*)d_in[19];
  const float* be2   = (const float*)d_in[20];

  const int* row = eidx;
  const int* col = eidx + NE;

  // workspace carve-up
  float* Hb = (float*)d_ws;                             // [MPAD][256] f32
  unsigned short* Xb0 = (unsigned short*)(Hb + (size_t)MPAD*256);   // [MPAD][64]
  unsigned short* Xb  = Xb0 + (size_t)MPAD*64;                      // [MPAD][256]
  unsigned short* Wt0 = Xb  + (size_t)MPAD*256;                     // [256][64]
  unsigned short* Wt1 = Wt0 + 256*64;                               // [256][256]
  unsigned short* Wt2 = Wt1 + 256*256;                              // [64][256]
  float* AS  = (float*)(Wt2 + 64*256);                  // [NN][4]
  float* AD  = AS + (size_t)NN*4;
  int* deg   = (int*)(AD + (size_t)NN*4);
  int* off   = deg + NN;                                // NN+1
  int* cursor= off + NN + 1;
  int* esrc  = cursor + NN;                             // NE
  int* eid   = esrc + NE;                               // NE

  float* out = (float*)d_out;

  // CSR build
  hipMemsetAsync(deg, 0, NN*sizeof(int), stream);
  k_hist<<<(NE+255)/256, 256, 0, stream>>>(col, deg);
  k_scan<<<1, 1024, 0, stream>>>(deg, off, cursor);
  k_scatter<<<(NE+255)/256, 256, 0, stream>>>(row, col, cursor, esrc, eid);

  // W conversions (tiny)
  k_wconv<<<(256*64 +255)/256, 256, 0, stream>>>(W0, Wt0, 64, 256);
  k_wconv<<<(256*256+255)/256, 256, 0, stream>>>(W1, Wt1, 256, 256);
  k_wconv<<<(64*256 +255)/256, 256, 0, stream>>>(W2, Wt2, 256, 64);

  // x = node + scatter_mean(edge_embeds)  -> bf16
  int nwaveblk = (NN*64 + 255)/256;
  k_premix<<<nwaveblk, 256, 0, stream>>>(node, ee, off, eid, Xb0);

  // ---- layer 0: K=64, heads=4, Nc=256 ----
  {
    dim3 g(256/128, MPAD/128);
    k_gemm_mfma<128,64><<<g, 256, 0, stream>>>(Xb0, Wt0, Hb, 256);
    k_coef<4><<<nwaveblk, 256, 0, stream>>>(Hb, asrc0, adst0, AS, AD);
    k_agg<4,true><<<nwaveblk, 256, 0, stream>>>(Hb, AS, AD, off, esrc, b0, g0, be0, Xb);
  }
  // ---- layer 1: K=256, heads=4, Nc=256 ----
  {
    dim3 g(256/128, MPAD/128);
    k_gemm_mfma<128,256><<<g, 256, 0, stream>>>(Xb, Wt1, Hb, 256);
    k_coef<4><<<nwaveblk, 256, 0, stream>>>(Hb, asrc1, adst1, AS, AD);
    k_agg<4,true><<<nwaveblk, 256, 0, stream>>>(Hb, AS, AD, off, esrc, b1, g1, be1, Xb);
  }
  // ---- layer 2: K=256, heads=1, Nc=64, concat=False (mean of 1 head = identity) ----
  {
    dim3 g(64/64, MPAD/128);
    k_gemm_mfma<64,256><<<g, 256, 0, stream>>>(Xb, Wt2, Hb, 64);
    k_coef<1><<<nwaveblk, 256, 0, stream>>>(Hb, asrc2, adst2, AS, AD);
    k_agg<1,false><<<nwaveblk, 256, 0, stream>>>(Hb, AS, AD, off, esrc, b2, g2, be2, out);
  }
}

// Round 3
// 670.951 us; speedup vs baseline: 1.5372x; 1.2260x over previous
//
#include <hip/hip_runtime.h>
#include <math.h>

#define NN 50000
#define NE 800000
#define MPAD 50048   // 391 * 128

typedef __attribute__((ext_vector_type(8))) short bf16x8;
typedef __attribute__((ext_vector_type(4))) float f32x4;

__device__ __forceinline__ float leaky(float x){ return x > 0.f ? x : 0.2f*x; }

__device__ __forceinline__ unsigned short f2bf(float f){
  unsigned int u = __float_as_uint(f);
  unsigned int r = (u + 0x7fffu + ((u >> 16) & 1u)) >> 16;
  return (unsigned short)r;
}
__device__ __forceinline__ float bf2f(unsigned short u){
  return __uint_as_float(((unsigned int)u) << 16);
}

// ---------------- CSR build ----------------
__global__ void k_hist(const int* __restrict__ col, int* __restrict__ deg){
  int e = blockIdx.x*blockDim.x + threadIdx.x;
  if (e < NE) atomicAdd(&deg[col[e]], 1);
}

__global__ void k_scan(const int* __restrict__ deg, int* __restrict__ off, int* __restrict__ cursor){
  __shared__ int buf[1024];
  __shared__ int carry_s;
  if (threadIdx.x==0) carry_s = 0;
  __syncthreads();
  for (int base=0; base<NN; base+=1024){
    int i = base + (int)threadIdx.x;
    int v = (i<NN)? deg[i] : 0;
    buf[threadIdx.x] = v;
    __syncthreads();
    for (int s=1;s<1024;s<<=1){
      int t = (threadIdx.x >= (unsigned)s)? buf[threadIdx.x-s] : 0;
      __syncthreads();
      buf[threadIdx.x] += t;
      __syncthreads();
    }
    int excl = carry_s + buf[threadIdx.x] - v;
    if (i<NN){ off[i]=excl; cursor[i]=excl; }
    __syncthreads();
    if (threadIdx.x==1023) carry_s += buf[1023];
    __syncthreads();
  }
  if (threadIdx.x==0) off[NN]=carry_s;
}

__global__ void k_scatter(const int* __restrict__ row, const int* __restrict__ col,
                          int* __restrict__ cursor, int* __restrict__ esrc, int* __restrict__ eid){
  int e = blockIdx.x*blockDim.x + threadIdx.x;
  if (e < NE){
    int c = col[e];
    int pos = atomicAdd(&cursor[c], 1);
    esrc[pos] = row[e];
    eid[pos]  = e;
  }
}

// ---------------- scatter-mean of edge embeds onto nodes (bf16 out) ----------------
__global__ void k_premix(const float* __restrict__ node, const float* __restrict__ ee,
                         const int* __restrict__ off, const int* __restrict__ eid,
                         unsigned short* __restrict__ Xb){
  int wid  = (int)((blockIdx.x*blockDim.x + threadIdx.x) >> 6);
  int lane = threadIdx.x & 63;
  if (wid >= NN) return;
  int s0 = off[wid], s1 = off[wid+1];
  float acc = 0.f;
  for (int p=s0; p<s1; ++p){
    int ed = eid[p];
    acc += ee[(size_t)ed*64 + lane];
  }
  float c = (float)((s1-s0) > 1 ? (s1-s0) : 1);
  Xb[(size_t)wid*64 + lane] = f2bf(node[(size_t)wid*64 + lane] + acc / c);
}

// ---------------- W convert+transpose: Wt[n][k] bf16 from W[k][n] f32 ----------------
__global__ void k_wconv(const float* __restrict__ W, unsigned short* __restrict__ Wt,
                        int K, int Ncols){
  int idx = blockIdx.x*blockDim.x + threadIdx.x;
  if (idx < K*Ncols){
    int n = idx / K, k = idx - n*K;
    Wt[idx] = f2bf(W[(size_t)k*Ncols + n]);
  }
}

// ---------------- bf16 MFMA GEMM: C[M,Nc] = A[M,K] * Bt[Nc,K]^T, bf16 out ----------------
template<int BN, int K>
__global__ __launch_bounds__(256)
void k_gemm_mfma(const unsigned short* __restrict__ A,
                 const unsigned short* __restrict__ Bt,
                 unsigned short* __restrict__ C, int Nc){
  constexpr int BM = 128, BK = 32;
  constexpr int WNT = BN/32;            // 16-col frags per wave (2x2 waves)
  __shared__ __align__(16) unsigned short As[BM*BK];
  __shared__ __align__(16) unsigned short Bs[BN*BK];
  const int tid  = threadIdx.x;
  const int lane = tid & 63;
  const int wid  = tid >> 6;
  const int wr   = wid >> 1, wc = wid & 1;
  const int bm   = blockIdx.y * BM, bn = blockIdx.x * BN;
  const int r    = lane >> 2, kq = lane & 3;   // staging: 4 lanes per 64B row

  f32x4 acc[4][WNT];
  #pragma unroll
  for (int i=0;i<4;++i)
    #pragma unroll
    for (int j=0;j<WNT;++j) acc[i][j] = (f32x4){0.f,0.f,0.f,0.f};

  for (int k0=0; k0<K; k0+=BK){
    #pragma unroll
    for (int i=0;i<2;++i){
      int arow = wid*32 + i*16 + r;
      __builtin_amdgcn_global_load_lds(
        (const __attribute__((address_space(1))) void*)(A + (size_t)(bm+arow)*K + k0 + kq*8),
        (__attribute__((address_space(3))) void*)&As[(wid*32 + i*16)*BK],
        16, 0, 0);
    }
    #pragma unroll
    for (int i=0;i<BN/64;++i){
      int brow = wid*(BN/4) + i*16 + r;
      __builtin_amdgcn_global_load_lds(
        (const __attribute__((address_space(1))) void*)(Bt + (size_t)(bn+brow)*K + k0 + kq*8),
        (__attribute__((address_space(3))) void*)&Bs[(wid*(BN/4) + i*16)*BK],
        16, 0, 0);
    }
    __syncthreads();

    bf16x8 af[4], bfr[WNT];
    #pragma unroll
    for (int mi=0; mi<4; ++mi)
      af[mi] = *reinterpret_cast<const bf16x8*>(&As[(wr*64 + mi*16 + (lane&15))*BK + (lane>>4)*8]);
    #pragma unroll
    for (int ni=0; ni<WNT; ++ni)
      bfr[ni] = *reinterpret_cast<const bf16x8*>(&Bs[(wc*(BN/2) + ni*16 + (lane&15))*BK + (lane>>4)*8]);
    #pragma unroll
    for (int mi=0; mi<4; ++mi)
      #pragma unroll
      for (int ni=0; ni<WNT; ++ni)
        acc[mi][ni] = __builtin_amdgcn_mfma_f32_16x16x32_bf16(af[mi], bfr[ni], acc[mi][ni], 0, 0, 0);
    __syncthreads();
  }

  #pragma unroll
  for (int mi=0; mi<4; ++mi){
    #pragma unroll
    for (int ni=0; ni<WNT; ++ni){
      int ccol = bn + wc*(BN/2) + ni*16 + (lane&15);
      int rbase = bm + wr*64 + mi*16 + (lane>>4)*4;
      #pragma unroll
      for (int reg=0; reg<4; ++reg)
        C[(size_t)(rbase+reg)*Nc + ccol] = f2bf(acc[mi][ni][reg]);
    }
  }
}

// ---------------- per-node attention coefficients a_s, a_d (bf16 H) ----------------
template<int HEADS>
__global__ void k_coef(const unsigned short* __restrict__ Hb, const float* __restrict__ asrc,
                       const float* __restrict__ adst,
                       float* __restrict__ AS, float* __restrict__ AD){
  constexpr int D   = HEADS*64;
  constexpr int VPL = D/64;
  constexpr int G   = 64/HEADS;
  int wid  = (int)((blockIdx.x*blockDim.x + threadIdx.x) >> 6);
  int lane = threadIdx.x & 63;
  if (wid >= NN) return;
  float s_=0.f, d_=0.f;
  if constexpr (VPL==4){
    ushort4 hv = *reinterpret_cast<const ushort4*>(Hb + (size_t)wid*D + lane*4);
    unsigned short hs[4] = {hv.x, hv.y, hv.z, hv.w};
    #pragma unroll
    for (int v=0; v<4; ++v){
      int idx = lane*4 + v;
      float h = bf2f(hs[v]);
      s_ += h * asrc[idx];
      d_ += h * adst[idx];
    }
  } else {
    float h = bf2f(Hb[(size_t)wid*D + lane]);
    s_ = h * asrc[lane];
    d_ = h * adst[lane];
  }
  #pragma unroll
  for (int mk=1; mk<G; mk<<=1){
    s_ += __shfl_xor(s_, mk, 64);
    d_ += __shfl_xor(d_, mk, 64);
  }
  if ((lane & (G-1)) == 0){
    int head = lane / G;
    AS[(size_t)wid*HEADS + head] = s_;
    AD[(size_t)wid*HEADS + head] = d_;
  }
}

// ---------------- online-softmax aggregation + bias + LN + ELU (bf16 H) ----------------
template<int HEADS, bool OUT_BF16>
__global__ void k_agg(const unsigned short* __restrict__ Hb, const float* __restrict__ AS,
                      const float* __restrict__ AD, const int* __restrict__ off,
                      const int* __restrict__ esrc,
                      const float* __restrict__ bias, const float* __restrict__ gamma,
                      const float* __restrict__ beta, void* __restrict__ OutP){
  constexpr int D   = HEADS*64;
  constexpr int VPL = D/64;
  int wid  = (int)((blockIdx.x*blockDim.x + threadIdx.x) >> 6);
  int lane = threadIdx.x & 63;
  if (wid >= NN) return;
  int head = (lane*VPL) >> 6;
  float ad = AD[(size_t)wid*HEADS + head];
  float wself = leaky(AS[(size_t)wid*HEADS + head] + ad);
  int s0 = off[wid], s1 = off[wid+1];

  // init with self-loop (pw = 1 at m = wself)
  float m = wself;
  float psum = 1.f;
  float acc[VPL];
  if constexpr (VPL==4){
    ushort4 hv = *reinterpret_cast<const ushort4*>(Hb + (size_t)wid*D + lane*4);
    acc[0]=bf2f(hv.x); acc[1]=bf2f(hv.y); acc[2]=bf2f(hv.z); acc[3]=bf2f(hv.w);
  } else {
    acc[0] = bf2f(Hb[(size_t)wid*D + lane]);
  }

  // single online pass over in-edges
  for (int p=s0; p<s1; ++p){
    int src = esrc[p];
    float w = leaky(AS[(size_t)src*HEADS + head] + ad);
    float mn = fmaxf(m, w);
    float scale = __expf(m - mn);
    float pw    = __expf(w - mn);
    m = mn;
    psum = psum*scale + pw;
    if constexpr (VPL==4){
      ushort4 hv = *reinterpret_cast<const ushort4*>(Hb + (size_t)src*D + lane*4);
      acc[0] = acc[0]*scale + pw*bf2f(hv.x);
      acc[1] = acc[1]*scale + pw*bf2f(hv.y);
      acc[2] = acc[2]*scale + pw*bf2f(hv.z);
      acc[3] = acc[3]*scale + pw*bf2f(hv.w);
    } else {
      acc[0] = acc[0]*scale + pw*bf2f(Hb[(size_t)src*D + lane]);
    }
  }

  float inv = 1.f/psum;
  float val[VPL];
  float s=0.f, s2=0.f;
  #pragma unroll
  for (int v=0;v<VPL;++v){
    val[v] = acc[v]*inv + bias[lane*VPL+v];
    s  += val[v];
    s2 += val[v]*val[v];
  }
  #pragma unroll
  for (int mk=1; mk<64; mk<<=1){
    s  += __shfl_xor(s,  mk, 64);
    s2 += __shfl_xor(s2, mk, 64);
  }
  float mean = s/(float)D;
  float var  = s2/(float)D - mean*mean;
  float rstd = rsqrtf(var + 1e-5f);
  #pragma unroll
  for (int v=0;v<VPL;++v){
    float y = (val[v]-mean)*rstd*gamma[lane*VPL+v] + beta[lane*VPL+v];
    y = (y > 0.f) ? y : expm1f(y);
    if constexpr (OUT_BF16)
      ((unsigned short*)OutP)[(size_t)wid*D + lane*VPL+v] = f2bf(y);
    else
      ((float*)OutP)[(size_t)wid*D + lane*VPL+v] = y;
  }
}

// ---------------- launcher ----------------
extern "C" void kernel_launch(void* const* d_in, const int* in_sizes, int n_in,
                              void* d_out, int out_size, void* d_ws, size_t ws_size,
                              hipStream_t stream) {
  const float* node  = (const float*)d_in[0];
  const int*   eidx  = (const int*)d_in[1];
  const float* ee    = (const float*)d_in[2];
  const float* W0    = (const float*)d_in[3];
  const float* asrc0 = (const float*)d_in[4];
  const float* adst0 = (const float*)d_in[5];
  const float* b0    = (const float*)d_in[6];
  const float* g0    = (const float*)d_in[7];
  const float* be0   = (const float*)d_in[8];
  const float* W1    = (const float*)d_in[9];
  const float* asrc1 = (const float*)d_in[10];
  const float* adst1 = (const float*)d_in[11];
  const float* b1    = (const float*)d_in[12];
  const float* g1    = (const float*)d_in[13];
  const float* be1   = (const float*)d_in[14];
  const float* W2    = (const float*)d_in[15];
  const float* asrc2 = (const float*)d_in[16];
  const float* adst2 = (const float*)d_in[17];
  const float* b2    = (const float*)d_in[18];
  const float* g2    = (const float*)d_in[19];
  const float* be2   = (const float*)d_in[20];

  const int* row = eidx;
  const int* col = eidx + NE;

  // workspace carve-up (all bf16 activations)
  unsigned short* Hb  = (unsigned short*)d_ws;          // [MPAD][256] bf16
  unsigned short* Xb0 = Hb  + (size_t)MPAD*256;         // [MPAD][64]
  unsigned short* Xb  = Xb0 + (size_t)MPAD*64;          // [MPAD][256]
  unsigned short* Wt0 = Xb  + (size_t)MPAD*256;         // [256][64]
  unsigned short* Wt1 = Wt0 + 256*64;                   // [256][256]
  unsigned short* Wt2 = Wt1 + 256*256;                  // [64][256]
  float* AS  = (float*)(Wt2 + 64*256);                  // [NN][4]
  float* AD  = AS + (size_t)NN*4;
  int* deg   = (int*)(AD + (size_t)NN*4);
  int* off   = deg + NN;                                // NN+1
  int* cursor= off + NN + 1;
  int* esrc  = cursor + NN;                             // NE
  int* eid   = esrc + NE;                               // NE

  float* out = (float*)d_out;

  // CSR build
  hipMemsetAsync(deg, 0, NN*sizeof(int), stream);
  k_hist<<<(NE+255)/256, 256, 0, stream>>>(col, deg);
  k_scan<<<1, 1024, 0, stream>>>(deg, off, cursor);
  k_scatter<<<(NE+255)/256, 256, 0, stream>>>(row, col, cursor, esrc, eid);

  // W conversions (tiny)
  k_wconv<<<(256*64 +255)/256, 256, 0, stream>>>(W0, Wt0, 64, 256);
  k_wconv<<<(256*256+255)/256, 256, 0, stream>>>(W1, Wt1, 256, 256);
  k_wconv<<<(64*256 +255)/256, 256, 0, stream>>>(W2, Wt2, 256, 64);

  // x = node + scatter_mean(edge_embeds)  -> bf16
  int nwaveblk = (NN*64 + 255)/256;
  k_premix<<<nwaveblk, 256, 0, stream>>>(node, ee, off, eid, Xb0);

  // ---- layer 0: K=64, heads=4, Nc=256 ----
  {
    dim3 g(256/128, MPAD/128);
    k_gemm_mfma<128,64><<<g, 256, 0, stream>>>(Xb0, Wt0, Hb, 256);
    k_coef<4><<<nwaveblk, 256, 0, stream>>>(Hb, asrc0, adst0, AS, AD);
    k_agg<4,true><<<nwaveblk, 256, 0, stream>>>(Hb, AS, AD, off, esrc, b0, g0, be0, Xb);
  }
  // ---- layer 1: K=256, heads=4, Nc=256 ----
  {
    dim3 g(256/128, MPAD/128);
    k_gemm_mfma<128,256><<<g, 256, 0, stream>>>(Xb, Wt1, Hb, 256);
    k_coef<4><<<nwaveblk, 256, 0, stream>>>(Hb, asrc1, adst1, AS, AD);
    k_agg<4,true><<<nwaveblk, 256, 0, stream>>>(Hb, AS, AD, off, esrc, b1, g1, be1, Xb);
  }
  // ---- layer 2: K=256, heads=1, Nc=64, concat=False (mean of 1 head = identity) ----
  {
    dim3 g(64/64, MPAD/128);
    k_gemm_mfma<64,256><<<g, 256, 0, stream>>>(Xb, Wt2, Hb, 64);
    k_coef<1><<<nwaveblk, 256, 0, stream>>>(Hb, asrc2, adst2, AS, AD);
    k_agg<1,false><<<nwaveblk, 256, 0, stream>>>(Hb, AS, AD, off, esrc, b2, g2, be2, out);
  }
}

// Round 4
// 541.026 us; speedup vs baseline: 1.9063x; 1.2401x over previous
//
#include <hip/hip_runtime.h>
#include <math.h>

#define NN 50000
#define NE 800000
#define MPAD 50048   // 391 * 128

typedef __attribute__((ext_vector_type(8))) short bf16x8;
typedef __attribute__((ext_vector_type(8))) unsigned short u16x8;
typedef __attribute__((ext_vector_type(4))) float f32x4;

__device__ __forceinline__ float leaky(float x){ return x > 0.f ? x : 0.2f*x; }

__device__ __forceinline__ unsigned short f2bf(float f){
  unsigned int u = __float_as_uint(f);
  unsigned int r = (u + 0x7fffu + ((u >> 16) & 1u)) >> 16;
  return (unsigned short)r;
}
__device__ __forceinline__ float bf2f(unsigned short u){
  return __uint_as_float(((unsigned int)u) << 16);
}

// ---------------- CSR build ----------------
__global__ void k_hist(const int* __restrict__ col, int* __restrict__ deg){
  int e = blockIdx.x*blockDim.x + threadIdx.x;
  if (e < NE) atomicAdd(&deg[col[e]], 1);
}

__global__ void k_scan(const int* __restrict__ deg, int* __restrict__ off, int* __restrict__ cursor){
  __shared__ int buf[1024];
  __shared__ int carry_s;
  if (threadIdx.x==0) carry_s = 0;
  __syncthreads();
  for (int base=0; base<NN; base+=1024){
    int i = base + (int)threadIdx.x;
    int v = (i<NN)? deg[i] : 0;
    buf[threadIdx.x] = v;
    __syncthreads();
    for (int s=1;s<1024;s<<=1){
      int t = (threadIdx.x >= (unsigned)s)? buf[threadIdx.x-s] : 0;
      __syncthreads();
      buf[threadIdx.x] += t;
      __syncthreads();
    }
    int excl = carry_s + buf[threadIdx.x] - v;
    if (i<NN){ off[i]=excl; cursor[i]=excl; }
    __syncthreads();
    if (threadIdx.x==1023) carry_s += buf[1023];
    __syncthreads();
  }
  if (threadIdx.x==0) off[NN]=carry_s;
}

__global__ void k_scatter(const int* __restrict__ row, const int* __restrict__ col,
                          int* __restrict__ cursor, int* __restrict__ esrc, int* __restrict__ eid){
  int e = blockIdx.x*blockDim.x + threadIdx.x;
  if (e < NE){
    int c = col[e];
    int pos = atomicAdd(&cursor[c], 1);
    esrc[pos] = row[e];
    eid[pos]  = e;
  }
}

// ---------------- scatter-mean of edge embeds (4 edges in flight per wave) ----------------
__global__ void k_premix(const float* __restrict__ node, const float* __restrict__ ee,
                         const int* __restrict__ off, const int* __restrict__ eid,
                         unsigned short* __restrict__ Xb){
  int wid  = (int)((blockIdx.x*blockDim.x + threadIdx.x) >> 6);
  int lane = threadIdx.x & 63;
  if (wid >= NN) return;
  int g   = lane >> 4;          // 4 groups of 16 lanes
  int l16 = lane & 15;          // group lane: covers cols l16*4..+3
  int s0 = off[wid], s1 = off[wid+1];

  float a0=0.f, a1=0.f, a2=0.f, a3=0.f;
  for (int p = s0 + g; p < s1; p += 4){
    int ed = eid[p];
    float4 hv = *reinterpret_cast<const float4*>(ee + (size_t)ed*64 + l16*4);
    a0 += hv.x; a1 += hv.y; a2 += hv.z; a3 += hv.w;
  }
  // merge 4 groups
  #pragma unroll
  for (int mk=16; mk<64; mk<<=1){
    a0 += __shfl_xor(a0, mk, 64);
    a1 += __shfl_xor(a1, mk, 64);
    a2 += __shfl_xor(a2, mk, 64);
    a3 += __shfl_xor(a3, mk, 64);
  }
  if (lane < 16){
    int dcnt = s1 - s0;
    float c = (float)(dcnt > 1 ? dcnt : 1);
    float4 nv = *reinterpret_cast<const float4*>(node + (size_t)wid*64 + l16*4);
    ushort4 o;
    o.x = f2bf(nv.x + a0 / c);
    o.y = f2bf(nv.y + a1 / c);
    o.z = f2bf(nv.z + a2 / c);
    o.w = f2bf(nv.w + a3 / c);
    *reinterpret_cast<ushort4*>(Xb + (size_t)wid*64 + l16*4) = o;
  }
}

// ---------------- W convert+transpose: Wt[n][k] bf16 from W[k][n] f32 ----------------
__global__ void k_wconv(const float* __restrict__ W, unsigned short* __restrict__ Wt,
                        int K, int Ncols){
  int idx = blockIdx.x*blockDim.x + threadIdx.x;
  if (idx < K*Ncols){
    int n = idx / K, k = idx - n*K;
    Wt[idx] = f2bf(W[(size_t)k*Ncols + n]);
  }
}

// ---------------- bf16 MFMA GEMM: C[M,Nc] = A[M,K] * Bt[Nc,K]^T, bf16 out ----------------
template<int BN, int K>
__global__ __launch_bounds__(256)
void k_gemm_mfma(const unsigned short* __restrict__ A,
                 const unsigned short* __restrict__ Bt,
                 unsigned short* __restrict__ C, int Nc){
  constexpr int BM = 128, BK = 32;
  constexpr int WNT = BN/32;
  __shared__ __align__(16) unsigned short As[BM*BK];
  __shared__ __align__(16) unsigned short Bs[BN*BK];
  const int tid  = threadIdx.x;
  const int lane = tid & 63;
  const int wid  = tid >> 6;
  const int wr   = wid >> 1, wc = wid & 1;
  const int bm   = blockIdx.y * BM, bn = blockIdx.x * BN;
  const int r    = lane >> 2, kq = lane & 3;

  f32x4 acc[4][WNT];
  #pragma unroll
  for (int i=0;i<4;++i)
    #pragma unroll
    for (int j=0;j<WNT;++j) acc[i][j] = (f32x4){0.f,0.f,0.f,0.f};

  for (int k0=0; k0<K; k0+=BK){
    #pragma unroll
    for (int i=0;i<2;++i){
      int arow = wid*32 + i*16 + r;
      __builtin_amdgcn_global_load_lds(
        (const __attribute__((address_space(1))) void*)(A + (size_t)(bm+arow)*K + k0 + kq*8),
        (__attribute__((address_space(3))) void*)&As[(wid*32 + i*16)*BK],
        16, 0, 0);
    }
    #pragma unroll
    for (int i=0;i<BN/64;++i){
      int brow = wid*(BN/4) + i*16 + r;
      __builtin_amdgcn_global_load_lds(
        (const __attribute__((address_space(1))) void*)(Bt + (size_t)(bn+brow)*K + k0 + kq*8),
        (__attribute__((address_space(3))) void*)&Bs[(wid*(BN/4) + i*16)*BK],
        16, 0, 0);
    }
    __syncthreads();

    bf16x8 af[4], bfr[WNT];
    #pragma unroll
    for (int mi=0; mi<4; ++mi)
      af[mi] = *reinterpret_cast<const bf16x8*>(&As[(wr*64 + mi*16 + (lane&15))*BK + (lane>>4)*8]);
    #pragma unroll
    for (int ni=0; ni<WNT; ++ni)
      bfr[ni] = *reinterpret_cast<const bf16x8*>(&Bs[(wc*(BN/2) + ni*16 + (lane&15))*BK + (lane>>4)*8]);
    #pragma unroll
    for (int mi=0; mi<4; ++mi)
      #pragma unroll
      for (int ni=0; ni<WNT; ++ni)
        acc[mi][ni] = __builtin_amdgcn_mfma_f32_16x16x32_bf16(af[mi], bfr[ni], acc[mi][ni], 0, 0, 0);
    __syncthreads();
  }

  #pragma unroll
  for (int mi=0; mi<4; ++mi){
    #pragma unroll
    for (int ni=0; ni<WNT; ++ni){
      int ccol = bn + wc*(BN/2) + ni*16 + (lane&15);
      int rbase = bm + wr*64 + mi*16 + (lane>>4)*4;
      #pragma unroll
      for (int reg=0; reg<4; ++reg)
        C[(size_t)(rbase+reg)*Nc + ccol] = f2bf(acc[mi][ni][reg]);
    }
  }
}

// ---------------- per-node attention coefficients a_s, a_d (bf16 H) ----------------
template<int HEADS>
__global__ void k_coef(const unsigned short* __restrict__ Hb, const float* __restrict__ asrc,
                       const float* __restrict__ adst,
                       float* __restrict__ AS, float* __restrict__ AD){
  constexpr int D   = HEADS*64;
  constexpr int VPL = D/64;
  constexpr int G   = 64/HEADS;
  int wid  = (int)((blockIdx.x*blockDim.x + threadIdx.x) >> 6);
  int lane = threadIdx.x & 63;
  if (wid >= NN) return;
  float s_=0.f, d_=0.f;
  if constexpr (VPL==4){
    ushort4 hv = *reinterpret_cast<const ushort4*>(Hb + (size_t)wid*D + lane*4);
    unsigned short hs[4] = {hv.x, hv.y, hv.z, hv.w};
    #pragma unroll
    for (int v=0; v<4; ++v){
      int idx = lane*4 + v;
      float h = bf2f(hs[v]);
      s_ += h * asrc[idx];
      d_ += h * adst[idx];
    }
  } else {
    float h = bf2f(Hb[(size_t)wid*D + lane]);
    s_ = h * asrc[lane];
    d_ = h * adst[lane];
  }
  #pragma unroll
  for (int mk=1; mk<G; mk<<=1){
    s_ += __shfl_xor(s_, mk, 64);
    d_ += __shfl_xor(d_, mk, 64);
  }
  if ((lane & (G-1)) == 0){
    int head = lane / G;
    AS[(size_t)wid*HEADS + head] = s_;
    AD[(size_t)wid*HEADS + head] = d_;
  }
}

// ---------------- online-softmax aggregation, multi-edge in flight ----------------
// L lanes cover one row with C cols/lane; NG=64/L groups each run an independent
// online softmax over an edge subset; states merged via shfl at the end.
template<int HEADS, bool OUT_BF16>
__global__ void k_agg(const unsigned short* __restrict__ Hb, const float* __restrict__ AS,
                      const float* __restrict__ AD, const int* __restrict__ off,
                      const int* __restrict__ esrc,
                      const float* __restrict__ bias, const float* __restrict__ gamma,
                      const float* __restrict__ beta, void* __restrict__ OutP){
  constexpr int D  = HEADS*64;
  constexpr int L  = (HEADS==4) ? 32 : 16;   // lanes per row
  constexpr int C  = D / L;                  // cols per lane (8 or 4)
  constexpr int NG = 64 / L;                 // groups (2 or 4)
  int wid  = (int)((blockIdx.x*blockDim.x + threadIdx.x) >> 6);
  int lane = threadIdx.x & 63;
  if (wid >= NN) return;
  const int g    = lane / L;
  const int lrow = lane & (L-1);
  const int col0 = lrow * C;
  const int head = col0 >> 6;

  float ad    = AD[(size_t)wid*HEADS + head];
  float wself = leaky(AS[(size_t)wid*HEADS + head] + ad);
  int s0 = off[wid], s1 = off[wid+1];

  float m, psum;
  float acc[C];
  if (g == 0){
    m = wself; psum = 1.f;
    if constexpr (C==8){
      u16x8 hv = *reinterpret_cast<const u16x8*>(Hb + (size_t)wid*D + col0);
      #pragma unroll
      for (int v=0;v<8;++v) acc[v] = bf2f((unsigned short)hv[v]);
    } else {
      ushort4 hv = *reinterpret_cast<const ushort4*>(Hb + (size_t)wid*D + col0);
      acc[0]=bf2f(hv.x); acc[1]=bf2f(hv.y); acc[2]=bf2f(hv.z); acc[3]=bf2f(hv.w);
    }
  } else {
    m = -1e30f; psum = 0.f;
    #pragma unroll
    for (int v=0;v<C;++v) acc[v]=0.f;
  }

  for (int p = s0 + g; p < s1; p += NG){
    int src = esrc[p];
    float w = leaky(AS[(size_t)src*HEADS + head] + ad);
    float mn = fmaxf(m, w);
    float scale = __expf(m - mn);
    float pw    = __expf(w - mn);
    m = mn;
    psum = psum*scale + pw;
    if constexpr (C==8){
      u16x8 hv = *reinterpret_cast<const u16x8*>(Hb + (size_t)src*D + col0);
      #pragma unroll
      for (int v=0;v<8;++v) acc[v] = acc[v]*scale + pw*bf2f((unsigned short)hv[v]);
    } else {
      ushort4 hv = *reinterpret_cast<const ushort4*>(Hb + (size_t)src*D + col0);
      acc[0] = acc[0]*scale + pw*bf2f(hv.x);
      acc[1] = acc[1]*scale + pw*bf2f(hv.y);
      acc[2] = acc[2]*scale + pw*bf2f(hv.z);
      acc[3] = acc[3]*scale + pw*bf2f(hv.w);
    }
  }

  // merge group states (associative online-softmax merge)
  #pragma unroll
  for (int mk=L; mk<64; mk<<=1){
    float m_o    = __shfl_xor(m, mk, 64);
    float psum_o = __shfl_xor(psum, mk, 64);
    float mn = fmaxf(m, m_o);
    float sA = __expf(m - mn);
    float sB = __expf(m_o - mn);
    psum = psum*sA + psum_o*sB;
    #pragma unroll
    for (int v=0;v<C;++v){
      float a_o = __shfl_xor(acc[v], mk, 64);
      acc[v] = acc[v]*sA + a_o*sB;
    }
    m = mn;
  }

  float inv = 1.f/psum;
  float val[C];
  float s=0.f, s2=0.f;
  #pragma unroll
  for (int v=0;v<C;++v){
    val[v] = acc[v]*inv + bias[col0+v];
    s  += val[v];
    s2 += val[v]*val[v];
  }
  #pragma unroll
  for (int mk=1; mk<64; mk<<=1){
    s  += __shfl_xor(s,  mk, 64);
    s2 += __shfl_xor(s2, mk, 64);
  }
  // each col counted 64*C/D times; uniform -> divide by 64*C
  float mean = s/(float)(64*C);
  float var  = s2/(float)(64*C) - mean*mean;
  float rstd = rsqrtf(var + 1e-5f);
  if (g == 0){
    if constexpr (OUT_BF16){
      u16x8 o;
      #pragma unroll
      for (int v=0;v<C;++v){
        float y = (val[v]-mean)*rstd*gamma[col0+v] + beta[col0+v];
        y = (y > 0.f) ? y : expm1f(y);
        o[v] = f2bf(y);
      }
      if constexpr (C==8){
        *reinterpret_cast<u16x8*>((unsigned short*)OutP + (size_t)wid*D + col0) = o;
      } else {
        ushort4 o4; o4.x=(unsigned short)o[0]; o4.y=(unsigned short)o[1];
        o4.z=(unsigned short)o[2]; o4.w=(unsigned short)o[3];
        *reinterpret_cast<ushort4*>((unsigned short*)OutP + (size_t)wid*D + col0) = o4;
      }
    } else {
      float o[C];
      #pragma unroll
      for (int v=0;v<C;++v){
        float y = (val[v]-mean)*rstd*gamma[col0+v] + beta[col0+v];
        o[v] = (y > 0.f) ? y : expm1f(y);
      }
      if constexpr (C==4){
        float4 o4 = {o[0],o[1],o[2],o[3]};
        *reinterpret_cast<float4*>((float*)OutP + (size_t)wid*D + col0) = o4;
      } else {
        #pragma unroll
        for (int v=0;v<C;++v) ((float*)OutP)[(size_t)wid*D + col0+v] = o[v];
      }
    }
  }
}

// ---------------- launcher ----------------
extern "C" void kernel_launch(void* const* d_in, const int* in_sizes, int n_in,
                              void* d_out, int out_size, void* d_ws, size_t ws_size,
                              hipStream_t stream) {
  const float* node  = (const float*)d_in[0];
  const int*   eidx  = (const int*)d_in[1];
  const float* ee    = (const float*)d_in[2];
  const float* W0    = (const float*)d_in[3];
  const float* asrc0 = (const float*)d_in[4];
  const float* adst0 = (const float*)d_in[5];
  const float* b0    = (const float*)d_in[6];
  const float* g0    = (const float*)d_in[7];
  const float* be0   = (const float*)d_in[8];
  const float* W1    = (const float*)d_in[9];
  const float* asrc1 = (const float*)d_in[10];
  const float* adst1 = (const float*)d_in[11];
  const float* b1    = (const float*)d_in[12];
  const float* g1    = (const float*)d_in[13];
  const float* be1   = (const float*)d_in[14];
  const float* W2    = (const float*)d_in[15];
  const float* asrc2 = (const float*)d_in[16];
  const float* adst2 = (const float*)d_in[17];
  const float* b2    = (const float*)d_in[18];
  const float* g2    = (const float*)d_in[19];
  const float* be2   = (const float*)d_in[20];

  const int* row = eidx;
  const int* col = eidx + NE;

  unsigned short* Hb  = (unsigned short*)d_ws;          // [MPAD][256] bf16
  unsigned short* Xb0 = Hb  + (size_t)MPAD*256;         // [MPAD][64]
  unsigned short* Xb  = Xb0 + (size_t)MPAD*64;          // [MPAD][256]
  unsigned short* Wt0 = Xb  + (size_t)MPAD*256;         // [256][64]
  unsigned short* Wt1 = Wt0 + 256*64;                   // [256][256]
  unsigned short* Wt2 = Wt1 + 256*256;                  // [64][256]
  float* AS  = (float*)(Wt2 + 64*256);                  // [NN][4]
  float* AD  = AS + (size_t)NN*4;
  int* deg   = (int*)(AD + (size_t)NN*4);
  int* off   = deg + NN;                                // NN+1
  int* cursor= off + NN + 1;
  int* esrc  = cursor + NN;                             // NE
  int* eid   = esrc + NE;                               // NE

  float* out = (float*)d_out;

  hipMemsetAsync(deg, 0, NN*sizeof(int), stream);
  k_hist<<<(NE+255)/256, 256, 0, stream>>>(col, deg);
  k_scan<<<1, 1024, 0, stream>>>(deg, off, cursor);
  k_scatter<<<(NE+255)/256, 256, 0, stream>>>(row, col, cursor, esrc, eid);

  k_wconv<<<(256*64 +255)/256, 256, 0, stream>>>(W0, Wt0, 64, 256);
  k_wconv<<<(256*256+255)/256, 256, 0, stream>>>(W1, Wt1, 256, 256);
  k_wconv<<<(64*256 +255)/256, 256, 0, stream>>>(W2, Wt2, 256, 64);

  int nwaveblk = (NN*64 + 255)/256;
  k_premix<<<nwaveblk, 256, 0, stream>>>(node, ee, off, eid, Xb0);

  // ---- layer 0: K=64, heads=4, Nc=256 ----
  {
    dim3 g(256/128, MPAD/128);
    k_gemm_mfma<128,64><<<g, 256, 0, stream>>>(Xb0, Wt0, Hb, 256);
    k_coef<4><<<nwaveblk, 256, 0, stream>>>(Hb, asrc0, adst0, AS, AD);
    k_agg<4,true><<<nwaveblk, 256, 0, stream>>>(Hb, AS, AD, off, esrc, b0, g0, be0, Xb);
  }
  // ---- layer 1: K=256, heads=4, Nc=256 ----
  {
    dim3 g(256/128, MPAD/128);
    k_gemm_mfma<128,256><<<g, 256, 0, stream>>>(Xb, Wt1, Hb, 256);
    k_coef<4><<<nwaveblk, 256, 0, stream>>>(Hb, asrc1, adst1, AS, AD);
    k_agg<4,true><<<nwaveblk, 256, 0, stream>>>(Hb, AS, AD, off, esrc, b1, g1, be1, Xb);
  }
  // ---- layer 2: K=256, heads=1, Nc=64, concat=False ----
  {
    dim3 g(64/64, MPAD/128);
    k_gemm_mfma<64,256><<<g, 256, 0, stream>>>(Xb, Wt2, Hb, 64);
    k_coef<1><<<nwaveblk, 256, 0, stream>>>(Hb, asrc2, adst2, AS, AD);
    k_agg<1,false><<<nwaveblk, 256, 0, stream>>>(Hb, AS, AD, off, esrc, b2, g2, be2, out);
  }
}

// Round 5
// 536.749 us; speedup vs baseline: 1.9215x; 1.0080x over previous
//
#include <hip/hip_runtime.h>
#include <math.h>

#define NN 50000
#define NE 800000
#define MPAD 50048   // 391 * 128

typedef __attribute__((ext_vector_type(8))) short bf16x8;
typedef __attribute__((ext_vector_type(8))) unsigned short u16x8;
typedef __attribute__((ext_vector_type(4))) float f32x4;

__device__ __forceinline__ float leaky(float x){ return x > 0.f ? x : 0.2f*x; }

__device__ __forceinline__ unsigned short f2bf(float f){
  unsigned int u = __float_as_uint(f);
  unsigned int r = (u + 0x7fffu + ((u >> 16) & 1u)) >> 16;
  return (unsigned short)r;
}
__device__ __forceinline__ float bf2f(unsigned short u){
  return __uint_as_float(((unsigned int)u) << 16);
}

// ---------------- CSR build ----------------
__global__ void k_zero(int* __restrict__ deg){
  int i = blockIdx.x*blockDim.x + threadIdx.x;
  if (i < NN) deg[i] = 0;
}

__global__ void k_hist(const int* __restrict__ col, int* __restrict__ deg){
  int e = blockIdx.x*blockDim.x + threadIdx.x;
  if (e < NE) atomicAdd(&deg[col[e]], 1);
}

__global__ void k_scan(const int* __restrict__ deg, int* __restrict__ off, int* __restrict__ cursor){
  __shared__ int buf[1024];
  __shared__ int carry_s;
  if (threadIdx.x==0) carry_s = 0;
  __syncthreads();
  for (int base=0; base<NN; base+=1024){
    int i = base + (int)threadIdx.x;
    int v = (i<NN)? deg[i] : 0;
    buf[threadIdx.x] = v;
    __syncthreads();
    for (int s=1;s<1024;s<<=1){
      int t = (threadIdx.x >= (unsigned)s)? buf[threadIdx.x-s] : 0;
      __syncthreads();
      buf[threadIdx.x] += t;
      __syncthreads();
    }
    int excl = carry_s + buf[threadIdx.x] - v;
    if (i<NN){ off[i]=excl; cursor[i]=excl; }
    __syncthreads();
    if (threadIdx.x==1023) carry_s += buf[1023];
    __syncthreads();
  }
  if (threadIdx.x==0) off[NN]=carry_s;
}

__global__ void k_scatter(const int* __restrict__ row, const int* __restrict__ col,
                          int* __restrict__ cursor, int* __restrict__ esrc, int* __restrict__ eid){
  int e = blockIdx.x*blockDim.x + threadIdx.x;
  if (e < NE){
    int c = col[e];
    int pos = atomicAdd(&cursor[c], 1);
    esrc[pos] = row[e];
    eid[pos]  = e;
  }
}

// ---------------- scatter-mean of edge embeds (4 edges in flight per wave) ----------------
__global__ void k_premix(const float* __restrict__ node, const float* __restrict__ ee,
                         const int* __restrict__ off, const int* __restrict__ eid,
                         unsigned short* __restrict__ Xb){
  int wid  = (int)((blockIdx.x*blockDim.x + threadIdx.x) >> 6);
  int lane = threadIdx.x & 63;
  if (wid >= NN) return;
  int g   = lane >> 4;          // 4 groups of 16 lanes
  int l16 = lane & 15;          // group lane: covers cols l16*4..+3
  int s0 = off[wid], s1 = off[wid+1];

  float a0=0.f, a1=0.f, a2=0.f, a3=0.f;
  for (int p = s0 + g; p < s1; p += 4){
    int ed = eid[p];
    float4 hv = *reinterpret_cast<const float4*>(ee + (size_t)ed*64 + l16*4);
    a0 += hv.x; a1 += hv.y; a2 += hv.z; a3 += hv.w;
  }
  // merge 4 groups
  #pragma unroll
  for (int mk=16; mk<64; mk<<=1){
    a0 += __shfl_xor(a0, mk, 64);
    a1 += __shfl_xor(a1, mk, 64);
    a2 += __shfl_xor(a2, mk, 64);
    a3 += __shfl_xor(a3, mk, 64);
  }
  if (lane < 16){
    int dcnt = s1 - s0;
    float c = (float)(dcnt > 1 ? dcnt : 1);
    float4 nv = *reinterpret_cast<const float4*>(node + (size_t)wid*64 + l16*4);
    ushort4 o;
    o.x = f2bf(nv.x + a0 / c);
    o.y = f2bf(nv.y + a1 / c);
    o.z = f2bf(nv.z + a2 / c);
    o.w = f2bf(nv.w + a3 / c);
    *reinterpret_cast<ushort4*>(Xb + (size_t)wid*64 + l16*4) = o;
  }
}

// ---------------- W convert+transpose: Wt[n][k] bf16 from W[k][n] f32 ----------------
__global__ void k_wconv(const float* __restrict__ W, unsigned short* __restrict__ Wt,
                        int K, int Ncols){
  int idx = blockIdx.x*blockDim.x + threadIdx.x;
  if (idx < K*Ncols){
    int n = idx / K, k = idx - n*K;
    Wt[idx] = f2bf(W[(size_t)k*Ncols + n]);
  }
}

// ---------------- bf16 MFMA GEMM: C[M,Nc] = A[M,K] * Bt[Nc,K]^T, bf16 out ----------------
template<int BN, int K>
__global__ __launch_bounds__(256)
void k_gemm_mfma(const unsigned short* __restrict__ A,
                 const unsigned short* __restrict__ Bt,
                 unsigned short* __restrict__ C, int Nc){
  constexpr int BM = 128, BK = 32;
  constexpr int WNT = BN/32;
  __shared__ __align__(16) unsigned short As[BM*BK];
  __shared__ __align__(16) unsigned short Bs[BN*BK];
  const int tid  = threadIdx.x;
  const int lane = tid & 63;
  const int wid  = tid >> 6;
  const int wr   = wid >> 1, wc = wid & 1;
  const int bm   = blockIdx.y * BM, bn = blockIdx.x * BN;
  const int r    = lane >> 2, kq = lane & 3;

  f32x4 acc[4][WNT];
  #pragma unroll
  for (int i=0;i<4;++i)
    #pragma unroll
    for (int j=0;j<WNT;++j) acc[i][j] = (f32x4){0.f,0.f,0.f,0.f};

  for (int k0=0; k0<K; k0+=BK){
    #pragma unroll
    for (int i=0;i<2;++i){
      int arow = wid*32 + i*16 + r;
      __builtin_amdgcn_global_load_lds(
        (const __attribute__((address_space(1))) void*)(A + (size_t)(bm+arow)*K + k0 + kq*8),
        (__attribute__((address_space(3))) void*)&As[(wid*32 + i*16)*BK],
        16, 0, 0);
    }
    #pragma unroll
    for (int i=0;i<BN/64;++i){
      int brow = wid*(BN/4) + i*16 + r;
      __builtin_amdgcn_global_load_lds(
        (const __attribute__((address_space(1))) void*)(Bt + (size_t)(bn+brow)*K + k0 + kq*8),
        (__attribute__((address_space(3))) void*)&Bs[(wid*(BN/4) + i*16)*BK],
        16, 0, 0);
    }
    __syncthreads();

    bf16x8 af[4], bfr[WNT];
    #pragma unroll
    for (int mi=0; mi<4; ++mi)
      af[mi] = *reinterpret_cast<const bf16x8*>(&As[(wr*64 + mi*16 + (lane&15))*BK + (lane>>4)*8]);
    #pragma unroll
    for (int ni=0; ni<WNT; ++ni)
      bfr[ni] = *reinterpret_cast<const bf16x8*>(&Bs[(wc*(BN/2) + ni*16 + (lane&15))*BK + (lane>>4)*8]);
    #pragma unroll
    for (int mi=0; mi<4; ++mi)
      #pragma unroll
      for (int ni=0; ni<WNT; ++ni)
        acc[mi][ni] = __builtin_amdgcn_mfma_f32_16x16x32_bf16(af[mi], bfr[ni], acc[mi][ni], 0, 0, 0);
    __syncthreads();
  }

  #pragma unroll
  for (int mi=0; mi<4; ++mi){
    #pragma unroll
    for (int ni=0; ni<WNT; ++ni){
      int ccol = bn + wc*(BN/2) + ni*16 + (lane&15);
      int rbase = bm + wr*64 + mi*16 + (lane>>4)*4;
      #pragma unroll
      for (int reg=0; reg<4; ++reg)
        C[(size_t)(rbase+reg)*Nc + ccol] = f2bf(acc[mi][ni][reg]);
    }
  }
}

// ---------------- per-node attention coefficients a_s, a_d (bf16 H) ----------------
template<int HEADS>
__global__ void k_coef(const unsigned short* __restrict__ Hb, const float* __restrict__ asrc,
                       const float* __restrict__ adst,
                       float* __restrict__ AS, float* __restrict__ AD){
  constexpr int D   = HEADS*64;
  constexpr int VPL = D/64;
  constexpr int G   = 64/HEADS;
  int wid  = (int)((blockIdx.x*blockDim.x + threadIdx.x) >> 6);
  int lane = threadIdx.x & 63;
  if (wid >= NN) return;
  float s_=0.f, d_=0.f;
  if constexpr (VPL==4){
    ushort4 hv = *reinterpret_cast<const ushort4*>(Hb + (size_t)wid*D + lane*4);
    unsigned short hs[4] = {hv.x, hv.y, hv.z, hv.w};
    #pragma unroll
    for (int v=0; v<4; ++v){
      int idx = lane*4 + v;
      float h = bf2f(hs[v]);
      s_ += h * asrc[idx];
      d_ += h * adst[idx];
    }
  } else {
    float h = bf2f(Hb[(size_t)wid*D + lane]);
    s_ = h * asrc[lane];
    d_ = h * adst[lane];
  }
  #pragma unroll
  for (int mk=1; mk<G; mk<<=1){
    s_ += __shfl_xor(s_, mk, 64);
    d_ += __shfl_xor(d_, mk, 64);
  }
  if ((lane & (G-1)) == 0){
    int head = lane / G;
    AS[(size_t)wid*HEADS + head] = s_;
    AD[(size_t)wid*HEADS + head] = d_;
  }
}

// ---------------- online-softmax aggregation, multi-edge in flight ----------------
template<int HEADS, bool OUT_BF16>
__global__ void k_agg(const unsigned short* __restrict__ Hb, const float* __restrict__ AS,
                      const float* __restrict__ AD, const int* __restrict__ off,
                      const int* __restrict__ esrc,
                      const float* __restrict__ bias, const float* __restrict__ gamma,
                      const float* __restrict__ beta, void* __restrict__ OutP){
  constexpr int D  = HEADS*64;
  constexpr int L  = (HEADS==4) ? 32 : 16;   // lanes per row
  constexpr int C  = D / L;                  // cols per lane (8 or 4)
  constexpr int NG = 64 / L;                 // groups (2 or 4)
  int wid  = (int)((blockIdx.x*blockDim.x + threadIdx.x) >> 6);
  int lane = threadIdx.x & 63;
  if (wid >= NN) return;
  const int g    = lane / L;
  const int lrow = lane & (L-1);
  const int col0 = lrow * C;
  const int head = col0 >> 6;

  float ad    = AD[(size_t)wid*HEADS + head];
  float wself = leaky(AS[(size_t)wid*HEADS + head] + ad);
  int s0 = off[wid], s1 = off[wid+1];

  float m, psum;
  float acc[C];
  if (g == 0){
    m = wself; psum = 1.f;
    if constexpr (C==8){
      u16x8 hv = *reinterpret_cast<const u16x8*>(Hb + (size_t)wid*D + col0);
      #pragma unroll
      for (int v=0;v<8;++v) acc[v] = bf2f((unsigned short)hv[v]);
    } else {
      ushort4 hv = *reinterpret_cast<const ushort4*>(Hb + (size_t)wid*D + col0);
      acc[0]=bf2f(hv.x); acc[1]=bf2f(hv.y); acc[2]=bf2f(hv.z); acc[3]=bf2f(hv.w);
    }
  } else {
    m = -1e30f; psum = 0.f;
    #pragma unroll
    for (int v=0;v<C;++v) acc[v]=0.f;
  }

  for (int p = s0 + g; p < s1; p += NG){
    int src = esrc[p];
    float w = leaky(AS[(size_t)src*HEADS + head] + ad);
    float mn = fmaxf(m, w);
    float scale = __expf(m - mn);
    float pw    = __expf(w - mn);
    m = mn;
    psum = psum*scale + pw;
    if constexpr (C==8){
      u16x8 hv = *reinterpret_cast<const u16x8*>(Hb + (size_t)src*D + col0);
      #pragma unroll
      for (int v=0;v<8;++v) acc[v] = acc[v]*scale + pw*bf2f((unsigned short)hv[v]);
    } else {
      ushort4 hv = *reinterpret_cast<const ushort4*>(Hb + (size_t)src*D + col0);
      acc[0] = acc[0]*scale + pw*bf2f(hv.x);
      acc[1] = acc[1]*scale + pw*bf2f(hv.y);
      acc[2] = acc[2]*scale + pw*bf2f(hv.z);
      acc[3] = acc[3]*scale + pw*bf2f(hv.w);
    }
  }

  // merge group states (associative online-softmax merge)
  #pragma unroll
  for (int mk=L; mk<64; mk<<=1){
    float m_o    = __shfl_xor(m, mk, 64);
    float psum_o = __shfl_xor(psum, mk, 64);
    float mn = fmaxf(m, m_o);
    float sA = __expf(m - mn);
    float sB = __expf(m_o - mn);
    psum = psum*sA + psum_o*sB;
    #pragma unroll
    for (int v=0;v<C;++v){
      float a_o = __shfl_xor(acc[v], mk, 64);
      acc[v] = acc[v]*sA + a_o*sB;
    }
    m = mn;
  }

  float inv = 1.f/psum;
  float val[C];
  float s=0.f, s2=0.f;
  #pragma unroll
  for (int v=0;v<C;++v){
    val[v] = acc[v]*inv + bias[col0+v];
    s  += val[v];
    s2 += val[v]*val[v];
  }
  #pragma unroll
  for (int mk=1; mk<64; mk<<=1){
    s  += __shfl_xor(s,  mk, 64);
    s2 += __shfl_xor(s2, mk, 64);
  }
  float mean = s/(float)(64*C);
  float var  = s2/(float)(64*C) - mean*mean;
  float rstd = rsqrtf(var + 1e-5f);
  if (g == 0){
    if constexpr (OUT_BF16){
      u16x8 o;
      #pragma unroll
      for (int v=0;v<C;++v){
        float y = (val[v]-mean)*rstd*gamma[col0+v] + beta[col0+v];
        y = (y > 0.f) ? y : expm1f(y);
        o[v] = f2bf(y);
      }
      if constexpr (C==8){
        *reinterpret_cast<u16x8*>((unsigned short*)OutP + (size_t)wid*D + col0) = o;
      } else {
        ushort4 o4; o4.x=(unsigned short)o[0]; o4.y=(unsigned short)o[1];
        o4.z=(unsigned short)o[2]; o4.w=(unsigned short)o[3];
        *reinterpret_cast<ushort4*>((unsigned short*)OutP + (size_t)wid*D + col0) = o4;
      }
    } else {
      float o[C];
      #pragma unroll
      for (int v=0;v<C;++v){
        float y = (val[v]-mean)*rstd*gamma[col0+v] + beta[col0+v];
        o[v] = (y > 0.f) ? y : expm1f(y);
      }
      if constexpr (C==4){
        float4 o4 = {o[0],o[1],o[2],o[3]};
        *reinterpret_cast<float4*>((float*)OutP + (size_t)wid*D + col0) = o4;
      } else {
        #pragma unroll
        for (int v=0;v<C;++v) ((float*)OutP)[(size_t)wid*D + col0+v] = o[v];
      }
    }
  }
}

// ---------------- launcher ----------------
extern "C" void kernel_launch(void* const* d_in, const int* in_sizes, int n_in,
                              void* d_out, int out_size, void* d_ws, size_t ws_size,
                              hipStream_t stream) {
  const float* node  = (const float*)d_in[0];
  const int*   eidx  = (const int*)d_in[1];
  const float* ee    = (const float*)d_in[2];
  const float* W0    = (const float*)d_in[3];
  const float* asrc0 = (const float*)d_in[4];
  const float* adst0 = (const float*)d_in[5];
  const float* b0    = (const float*)d_in[6];
  const float* g0    = (const float*)d_in[7];
  const float* be0   = (const float*)d_in[8];
  const float* W1    = (const float*)d_in[9];
  const float* asrc1 = (const float*)d_in[10];
  const float* adst1 = (const float*)d_in[11];
  const float* b1    = (const float*)d_in[12];
  const float* g1    = (const float*)d_in[13];
  const float* be1   = (const float*)d_in[14];
  const float* W2    = (const float*)d_in[15];
  const float* asrc2 = (const float*)d_in[16];
  const float* adst2 = (const float*)d_in[17];
  const float* b2    = (const float*)d_in[18];
  const float* g2    = (const float*)d_in[19];
  const float* be2   = (const float*)d_in[20];

  const int* row = eidx;
  const int* col = eidx + NE;

  unsigned short* Hb  = (unsigned short*)d_ws;          // [MPAD][256] bf16
  unsigned short* Xb0 = Hb  + (size_t)MPAD*256;         // [MPAD][64]
  unsigned short* Xb  = Xb0 + (size_t)MPAD*64;          // [MPAD][256]
  unsigned short* Wt0 = Xb  + (size_t)MPAD*256;         // [256][64]
  unsigned short* Wt1 = Wt0 + 256*64;                   // [256][256]
  unsigned short* Wt2 = Wt1 + 256*256;                  // [64][256]
  float* AS  = (float*)(Wt2 + 64*256);                  // [NN][4]
  float* AD  = AS + (size_t)NN*4;
  int* deg   = (int*)(AD + (size_t)NN*4);
  int* off   = deg + NN;                                // NN+1
  int* cursor= off + NN + 1;
  int* esrc  = cursor + NN;                             // NE
  int* eid   = esrc + NE;                               // NE

  float* out = (float*)d_out;

  k_zero<<<(NN+255)/256, 256, 0, stream>>>(deg);
  k_hist<<<(NE+255)/256, 256, 0, stream>>>(col, deg);
  k_scan<<<1, 1024, 0, stream>>>(deg, off, cursor);
  k_scatter<<<(NE+255)/256, 256, 0, stream>>>(row, col, cursor, esrc, eid);

  k_wconv<<<(256*64 +255)/256, 256, 0, stream>>>(W0, Wt0, 64, 256);
  k_wconv<<<(256*256+255)/256, 256, 0, stream>>>(W1, Wt1, 256, 256);
  k_wconv<<<(64*256 +255)/256, 256, 0, stream>>>(W2, Wt2, 256, 64);

  int nwaveblk = (NN*64 + 255)/256;
  k_premix<<<nwaveblk, 256, 0, stream>>>(node, ee, off, eid, Xb0);

  // ---- layer 0: K=64, heads=4, Nc=256 ----
  {
    dim3 g(256/128, MPAD/128);
    k_gemm_mfma<128,64><<<g, 256, 0, stream>>>(Xb0, Wt0, Hb, 256);
    k_coef<4><<<nwaveblk, 256, 0, stream>>>(Hb, asrc0, adst0, AS, AD);
    k_agg<4,true><<<nwaveblk, 256, 0, stream>>>(Hb, AS, AD, off, esrc, b0, g0, be0, Xb);
  }
  // ---- layer 1: K=256, heads=4, Nc=256 ----
  {
    dim3 g(256/128, MPAD/128);
    k_gemm_mfma<128,256><<<g, 256, 0, stream>>>(Xb, Wt1, Hb, 256);
    k_coef<4><<<nwaveblk, 256, 0, stream>>>(Hb, asrc1, adst1, AS, AD);
    k_agg<4,true><<<nwaveblk, 256, 0, stream>>>(Hb, AS, AD, off, esrc, b1, g1, be1, Xb);
  }
  // ---- layer 2: K=256, heads=1, Nc=64, concat=False ----
  {
    dim3 g(64/64, MPAD/128);
    k_gemm_mfma<64,256><<<g, 256, 0, stream>>>(Xb, Wt2, Hb, 64);
    k_coef<1><<<nwaveblk, 256, 0, stream>>>(Hb, asrc2, adst2, AS, AD);
    k_agg<1,false><<<nwaveblk, 256, 0, stream>>>(Hb, AS, AD, off, esrc, b2, g2, be2, out);
  }
}

// Round 6
// 497.348 us; speedup vs baseline: 2.0737x; 1.0792x over previous
//
#include <hip/hip_runtime.h>
#include <math.h>

#define NN 50000
#define NE 800000
#define MPAD 50048   // 391 * 128
#define NB 196       // ceil(NN/256)

typedef __attribute__((ext_vector_type(8))) short bf16x8;
typedef __attribute__((ext_vector_type(8))) unsigned short u16x8;
typedef __attribute__((ext_vector_type(4))) float f32x4;

__device__ __forceinline__ float leaky(float x){ return x > 0.f ? x : 0.2f*x; }

__device__ __forceinline__ unsigned short f2bf(float f){
  unsigned int u = __float_as_uint(f);
  unsigned int r = (u + 0x7fffu + ((u >> 16) & 1u)) >> 16;
  return (unsigned short)r;
}
__device__ __forceinline__ float bf2f(unsigned short u){
  return __uint_as_float(((unsigned int)u) << 16);
}

// ---------------- zero: deg + all AS/AD layer buffers ----------------
__global__ void k_zero(int* __restrict__ deg,
                       float* __restrict__ AS0, float* __restrict__ AD0,
                       float* __restrict__ AS1, float* __restrict__ AD1,
                       float* __restrict__ AS2, float* __restrict__ AD2){
  int i = blockIdx.x*blockDim.x + threadIdx.x;
  if (i < NN) deg[i] = 0;
  if (i < NN*4){
    AS0[i]=0.f; AD0[i]=0.f;
    AS1[i]=0.f; AD1[i]=0.f;
    AS2[i]=0.f; AD2[i]=0.f;
  }
}

// ---------------- CSR build ----------------
__global__ void k_hist(const int* __restrict__ col, int* __restrict__ deg){
  int e = blockIdx.x*blockDim.x + threadIdx.x;
  if (e < NE) atomicAdd(&deg[col[e]], 1);
}

// hierarchical scan: block-local
__global__ void k_scan1(const int* __restrict__ deg, int* __restrict__ off,
                        int* __restrict__ bsum){
  __shared__ int ws[4];
  int t = threadIdx.x;
  int i = blockIdx.x*256 + t;
  int v = (i<NN)? deg[i] : 0;
  int lane = t & 63, w = t >> 6;
  int x = v;
  #pragma unroll
  for (int d=1; d<64; d<<=1){
    int y = __shfl_up(x, d, 64);
    if (lane >= d) x += y;
  }
  if (lane==63) ws[w] = x;
  __syncthreads();
  int woff = 0;
  #pragma unroll
  for (int k=0;k<3;++k) if (k < w) woff += ws[k];
  int incl = x + woff;
  if (i<NN) off[i] = incl - v;
  if (t==255) bsum[blockIdx.x] = incl;
}

// scan of block sums (in place -> exclusive carries), writes off[NN]=total
__global__ void k_scan2(int* __restrict__ bsum, int* __restrict__ off){
  __shared__ int ws[4];
  int t = threadIdx.x;
  int v = (t<NB)? bsum[t] : 0;
  int lane = t & 63, w = t >> 6;
  int x = v;
  #pragma unroll
  for (int d=1; d<64; d<<=1){
    int y = __shfl_up(x, d, 64);
    if (lane >= d) x += y;
  }
  if (lane==63) ws[w] = x;
  __syncthreads();          // also guarantees all bsum reads done before writes
  int woff = 0;
  #pragma unroll
  for (int k=0;k<3;++k) if (k < w) woff += ws[k];
  int incl = x + woff;
  if (t<NB) bsum[t] = incl - v;
  if (t==NB-1) off[NN] = incl;
}

// add carries, fill cursor
__global__ void k_scan3(const int* __restrict__ bsum, int* __restrict__ off,
                        int* __restrict__ cursor){
  int i = blockIdx.x*256 + threadIdx.x;
  if (i<NN){
    int v = off[i] + bsum[blockIdx.x];
    off[i] = v;
    cursor[i] = v;
  }
}

__global__ void k_scatter(const int* __restrict__ row, const int* __restrict__ col,
                          int* __restrict__ cursor, int* __restrict__ esrc, int* __restrict__ eid){
  int e = blockIdx.x*blockDim.x + threadIdx.x;
  if (e < NE){
    int c = col[e];
    int pos = atomicAdd(&cursor[c], 1);
    esrc[pos] = row[e];
    eid[pos]  = e;
  }
}

// ---------------- scatter-mean of edge embeds (8 edges in flight per wave) ----------------
__global__ void k_premix(const float* __restrict__ node, const float* __restrict__ ee,
                         const int* __restrict__ off, const int* __restrict__ eid,
                         unsigned short* __restrict__ Xb){
  int wid  = (int)((blockIdx.x*blockDim.x + threadIdx.x) >> 6);
  int lane = threadIdx.x & 63;
  if (wid >= NN) return;
  int g  = lane >> 3;           // 8 groups
  int l8 = lane & 7;            // covers cols l8*8..+7
  int s0 = off[wid], s1 = off[wid+1];

  float a[8];
  #pragma unroll
  for (int v=0;v<8;++v) a[v]=0.f;
  for (int p = s0 + g; p < s1; p += 8){
    int ed = eid[p];
    const float4* rp = reinterpret_cast<const float4*>(ee + (size_t)ed*64 + l8*8);
    float4 h0 = rp[0], h1 = rp[1];
    a[0]+=h0.x; a[1]+=h0.y; a[2]+=h0.z; a[3]+=h0.w;
    a[4]+=h1.x; a[5]+=h1.y; a[6]+=h1.z; a[7]+=h1.w;
  }
  #pragma unroll
  for (int mk=8; mk<64; mk<<=1){
    #pragma unroll
    for (int v=0;v<8;++v) a[v] += __shfl_xor(a[v], mk, 64);
  }
  if (lane < 8){
    int dcnt = s1 - s0;
    float c = 1.f/(float)(dcnt > 1 ? dcnt : 1);
    const float4* np = reinterpret_cast<const float4*>(node + (size_t)wid*64 + l8*8);
    float4 n0 = np[0], n1 = np[1];
    float nv[8] = {n0.x,n0.y,n0.z,n0.w,n1.x,n1.y,n1.z,n1.w};
    u16x8 o;
    #pragma unroll
    for (int v=0;v<8;++v) o[v] = f2bf(nv[v] + a[v]*c);
    *reinterpret_cast<u16x8*>(Xb + (size_t)wid*64 + l8*8) = o;
  }
}

// ---------------- W convert+transpose: Wt[n][k] bf16 from W[k][n] f32 ----------------
__global__ void k_wconv(const float* __restrict__ W, unsigned short* __restrict__ Wt,
                        int K, int Ncols){
  int idx = blockIdx.x*blockDim.x + threadIdx.x;
  if (idx < K*Ncols){
    int n = idx / K, k = idx - n*K;
    Wt[idx] = f2bf(W[(size_t)k*Ncols + n]);
  }
}

// ---------------- bf16 MFMA GEMM + fused attention-coefficient epilogue ----------------
// C[M,Nc] = A[M,K] * Bt[Nc,K]^T (bf16 out); AS/AD += per-(row,head) partial dot
// with asrc/adst. Each wave's columns lie within one head (64-col span max).
template<int BN, int K, int HEADS>
__global__ __launch_bounds__(256)
void k_gemm_mfma(const unsigned short* __restrict__ A,
                 const unsigned short* __restrict__ Bt,
                 unsigned short* __restrict__ C,
                 const float* __restrict__ asrc, const float* __restrict__ adst,
                 float* __restrict__ AS, float* __restrict__ AD, int Nc){
  constexpr int BM = 128, BK = 32;
  constexpr int WNT = BN/32;
  __shared__ __align__(16) unsigned short As[BM*BK];
  __shared__ __align__(16) unsigned short Bs[BN*BK];
  const int tid  = threadIdx.x;
  const int lane = tid & 63;
  const int wid  = tid >> 6;
  const int wr   = wid >> 1, wc = wid & 1;
  const int bm   = blockIdx.y * BM, bn = blockIdx.x * BN;
  const int r    = lane >> 2, kq = lane & 3;

  f32x4 acc[4][WNT];
  #pragma unroll
  for (int i=0;i<4;++i)
    #pragma unroll
    for (int j=0;j<WNT;++j) acc[i][j] = (f32x4){0.f,0.f,0.f,0.f};

  for (int k0=0; k0<K; k0+=BK){
    #pragma unroll
    for (int i=0;i<2;++i){
      int arow = wid*32 + i*16 + r;
      __builtin_amdgcn_global_load_lds(
        (const __attribute__((address_space(1))) void*)(A + (size_t)(bm+arow)*K + k0 + kq*8),
        (__attribute__((address_space(3))) void*)&As[(wid*32 + i*16)*BK],
        16, 0, 0);
    }
    #pragma unroll
    for (int i=0;i<BN/64;++i){
      int brow = wid*(BN/4) + i*16 + r;
      __builtin_amdgcn_global_load_lds(
        (const __attribute__((address_space(1))) void*)(Bt + (size_t)(bn+brow)*K + k0 + kq*8),
        (__attribute__((address_space(3))) void*)&Bs[(wid*(BN/4) + i*16)*BK],
        16, 0, 0);
    }
    __syncthreads();

    bf16x8 af[4], bfr[WNT];
    #pragma unroll
    for (int mi=0; mi<4; ++mi)
      af[mi] = *reinterpret_cast<const bf16x8*>(&As[(wr*64 + mi*16 + (lane&15))*BK + (lane>>4)*8]);
    #pragma unroll
    for (int ni=0; ni<WNT; ++ni)
      bfr[ni] = *reinterpret_cast<const bf16x8*>(&Bs[(wc*(BN/2) + ni*16 + (lane&15))*BK + (lane>>4)*8]);
    #pragma unroll
    for (int mi=0; mi<4; ++mi)
      #pragma unroll
      for (int ni=0; ni<WNT; ++ni)
        acc[mi][ni] = __builtin_amdgcn_mfma_f32_16x16x32_bf16(af[mi], bfr[ni], acc[mi][ni], 0, 0, 0);
    __syncthreads();
  }

  // per-wave head and attention vectors for its columns
  const int head = (bn + wc*(BN/2)) >> 6;
  float av[WNT], dv[WNT];
  #pragma unroll
  for (int ni=0; ni<WNT; ++ni){
    int ccol = bn + wc*(BN/2) + ni*16 + (lane&15);
    av[ni] = asrc[ccol];
    dv[ni] = adst[ccol];
  }

  #pragma unroll
  for (int mi=0; mi<4; ++mi){
    // C write
    #pragma unroll
    for (int ni=0; ni<WNT; ++ni){
      int ccol = bn + wc*(BN/2) + ni*16 + (lane&15);
      int rbase = bm + wr*64 + mi*16 + (lane>>4)*4;
      #pragma unroll
      for (int reg=0; reg<4; ++reg)
        C[(size_t)(rbase+reg)*Nc + ccol] = f2bf(acc[mi][ni][reg]);
    }
    // fused a_s / a_d partials over this wave's 16*WNT columns
    float sp[4] = {0.f,0.f,0.f,0.f}, dp[4] = {0.f,0.f,0.f,0.f};
    #pragma unroll
    for (int ni=0; ni<WNT; ++ni)
      #pragma unroll
      for (int reg=0; reg<4; ++reg){
        sp[reg] += acc[mi][ni][reg]*av[ni];
        dp[reg] += acc[mi][ni][reg]*dv[ni];
      }
    #pragma unroll
    for (int reg=0; reg<4; ++reg)
      #pragma unroll
      for (int mk=1; mk<16; mk<<=1){
        sp[reg] += __shfl_xor(sp[reg], mk, 64);
        dp[reg] += __shfl_xor(dp[reg], mk, 64);
      }
    if ((lane & 15) == 0){
      int rr = bm + wr*64 + mi*16 + (lane>>4)*4;
      #pragma unroll
      for (int reg=0; reg<4; ++reg){
        atomicAdd(&AS[(size_t)(rr+reg)*HEADS + head], sp[reg]);
        atomicAdd(&AD[(size_t)(rr+reg)*HEADS + head], dp[reg]);
      }
    }
  }
}

// ---------------- online-softmax aggregation, multi-edge in flight ----------------
template<int HEADS, bool OUT_BF16>
__global__ void k_agg(const unsigned short* __restrict__ Hb, const float* __restrict__ AS,
                      const float* __restrict__ AD, const int* __restrict__ off,
                      const int* __restrict__ esrc,
                      const float* __restrict__ bias, const float* __restrict__ gamma,
                      const float* __restrict__ beta, void* __restrict__ OutP){
  constexpr int D  = HEADS*64;
  constexpr int L  = (HEADS==4) ? 16 : 8;    // lanes per row
  constexpr int C  = D / L;                  // cols per lane (16 or 8)
  constexpr int NG = 64 / L;                 // groups (4 or 8)
  constexpr int NV = C / 8;                  // u16x8 loads per lane (2 or 1)
  int wid  = (int)((blockIdx.x*blockDim.x + threadIdx.x) >> 6);
  int lane = threadIdx.x & 63;
  if (wid >= NN) return;
  const int g    = lane / L;
  const int lrow = lane & (L-1);
  const int col0 = lrow * C;
  const int head = col0 >> 6;

  float ad    = AD[(size_t)wid*HEADS + head];
  float wself = leaky(AS[(size_t)wid*HEADS + head] + ad);
  int s0 = off[wid], s1 = off[wid+1];

  float m, psum;
  float acc[C];
  if (g == 0){
    m = wself; psum = 1.f;
    const u16x8* hp = reinterpret_cast<const u16x8*>(Hb + (size_t)wid*D + col0);
    u16x8 hv[NV];
    #pragma unroll
    for (int q=0;q<NV;++q) hv[q] = hp[q];
    #pragma unroll
    for (int v=0;v<C;++v) acc[v] = bf2f((unsigned short)hv[v>>3][v&7]);
  } else {
    m = -1e30f; psum = 0.f;
    #pragma unroll
    for (int v=0;v<C;++v) acc[v]=0.f;
  }

  for (int p = s0 + g; p < s1; p += NG){
    int src = esrc[p];
    float w = leaky(AS[(size_t)src*HEADS + head] + ad);
    float mn = fmaxf(m, w);
    float scale = __expf(m - mn);
    float pw    = __expf(w - mn);
    m = mn;
    psum = psum*scale + pw;
    const u16x8* hp = reinterpret_cast<const u16x8*>(Hb + (size_t)src*D + col0);
    u16x8 hv[NV];
    #pragma unroll
    for (int q=0;q<NV;++q) hv[q] = hp[q];
    #pragma unroll
    for (int v=0;v<C;++v) acc[v] = acc[v]*scale + pw*bf2f((unsigned short)hv[v>>3][v&7]);
  }

  // merge group states (associative online-softmax merge)
  #pragma unroll
  for (int mk=L; mk<64; mk<<=1){
    float m_o    = __shfl_xor(m, mk, 64);
    float psum_o = __shfl_xor(psum, mk, 64);
    float mn = fmaxf(m, m_o);
    float sA = __expf(m - mn);
    float sB = __expf(m_o - mn);
    psum = psum*sA + psum_o*sB;
    #pragma unroll
    for (int v=0;v<C;++v){
      float a_o = __shfl_xor(acc[v], mk, 64);
      acc[v] = acc[v]*sA + a_o*sB;
    }
    m = mn;
  }

  float inv = 1.f/psum;
  float val[C];
  float s=0.f, s2=0.f;
  #pragma unroll
  for (int v=0;v<C;++v){
    val[v] = acc[v]*inv + bias[col0+v];
    s  += val[v];
    s2 += val[v]*val[v];
  }
  #pragma unroll
  for (int mk=1; mk<64; mk<<=1){
    s  += __shfl_xor(s,  mk, 64);
    s2 += __shfl_xor(s2, mk, 64);
  }
  float mean = s/(float)(64*C);
  float var  = s2/(float)(64*C) - mean*mean;
  float rstd = rsqrtf(var + 1e-5f);
  if (g == 0){
    if constexpr (OUT_BF16){
      u16x8 o[NV];
      #pragma unroll
      for (int v=0;v<C;++v){
        float y = (val[v]-mean)*rstd*gamma[col0+v] + beta[col0+v];
        y = (y > 0.f) ? y : expm1f(y);
        o[v>>3][v&7] = f2bf(y);
      }
      u16x8* op = reinterpret_cast<u16x8*>((unsigned short*)OutP + (size_t)wid*D + col0);
      #pragma unroll
      for (int q=0;q<NV;++q) op[q] = o[q];
    } else {
      float o[C];
      #pragma unroll
      for (int v=0;v<C;++v){
        float y = (val[v]-mean)*rstd*gamma[col0+v] + beta[col0+v];
        o[v] = (y > 0.f) ? y : expm1f(y);
      }
      float4* op = reinterpret_cast<float4*>((float*)OutP + (size_t)wid*D + col0);
      #pragma unroll
      for (int q=0;q<C/4;++q){
        float4 o4 = {o[q*4+0],o[q*4+1],o[q*4+2],o[q*4+3]};
        op[q] = o4;
      }
    }
  }
}

// ---------------- launcher ----------------
extern "C" void kernel_launch(void* const* d_in, const int* in_sizes, int n_in,
                              void* d_out, int out_size, void* d_ws, size_t ws_size,
                              hipStream_t stream) {
  const float* node  = (const float*)d_in[0];
  const int*   eidx  = (const int*)d_in[1];
  const float* ee    = (const float*)d_in[2];
  const float* W0    = (const float*)d_in[3];
  const float* asrc0 = (const float*)d_in[4];
  const float* adst0 = (const float*)d_in[5];
  const float* b0    = (const float*)d_in[6];
  const float* g0    = (const float*)d_in[7];
  const float* be0   = (const float*)d_in[8];
  const float* W1    = (const float*)d_in[9];
  const float* asrc1 = (const float*)d_in[10];
  const float* adst1 = (const float*)d_in[11];
  const float* b1    = (const float*)d_in[12];
  const float* g1    = (const float*)d_in[13];
  const float* be1   = (const float*)d_in[14];
  const float* W2    = (const float*)d_in[15];
  const float* asrc2 = (const float*)d_in[16];
  const float* adst2 = (const float*)d_in[17];
  const float* b2    = (const float*)d_in[18];
  const float* g2    = (const float*)d_in[19];
  const float* be2   = (const float*)d_in[20];

  const int* row = eidx;
  const int* col = eidx + NE;

  unsigned short* Hb  = (unsigned short*)d_ws;          // [MPAD][256] bf16
  unsigned short* Xb0 = Hb  + (size_t)MPAD*256;         // [MPAD][64]
  unsigned short* Xb  = Xb0 + (size_t)MPAD*64;          // [MPAD][256]
  unsigned short* Wt0 = Xb  + (size_t)MPAD*256;         // [256][64]
  unsigned short* Wt1 = Wt0 + 256*64;                   // [256][256]
  unsigned short* Wt2 = Wt1 + 256*256;                  // [64][256]
  float* AS0 = (float*)(Wt2 + 64*256);                  // [MPAD][4] each
  float* AD0 = AS0 + (size_t)MPAD*4;
  float* AS1 = AD0 + (size_t)MPAD*4;
  float* AD1 = AS1 + (size_t)MPAD*4;
  float* AS2 = AD1 + (size_t)MPAD*4;
  float* AD2 = AS2 + (size_t)MPAD*4;
  int* deg   = (int*)(AD2 + (size_t)MPAD*4);
  int* off   = deg + NN;                                // NN+1
  int* cursor= off + NN + 1;
  int* esrc  = cursor + NN;                             // NE
  int* eid   = esrc + NE;                               // NE
  int* bsum  = eid + NE;                                // NB

  float* out = (float*)d_out;

  k_zero<<<(NN*4+255)/256, 256, 0, stream>>>(deg, AS0, AD0, AS1, AD1, AS2, AD2);
  k_hist<<<(NE+255)/256, 256, 0, stream>>>(col, deg);
  k_scan1<<<NB, 256, 0, stream>>>(deg, off, bsum);
  k_scan2<<<1, 256, 0, stream>>>(bsum, off);
  k_scan3<<<NB, 256, 0, stream>>>(bsum, off, cursor);
  k_scatter<<<(NE+255)/256, 256, 0, stream>>>(row, col, cursor, esrc, eid);

  k_wconv<<<(256*64 +255)/256, 256, 0, stream>>>(W0, Wt0, 64, 256);
  k_wconv<<<(256*256+255)/256, 256, 0, stream>>>(W1, Wt1, 256, 256);
  k_wconv<<<(64*256 +255)/256, 256, 0, stream>>>(W2, Wt2, 256, 64);

  int nwaveblk = (NN*64 + 255)/256;
  k_premix<<<nwaveblk, 256, 0, stream>>>(node, ee, off, eid, Xb0);

  // ---- layer 0: K=64, heads=4, Nc=256 ----
  {
    dim3 g(256/128, MPAD/128);
    k_gemm_mfma<128,64,4><<<g, 256, 0, stream>>>(Xb0, Wt0, Hb, asrc0, adst0, AS0, AD0, 256);
    k_agg<4,true><<<nwaveblk, 256, 0, stream>>>(Hb, AS0, AD0, off, esrc, b0, g0, be0, Xb);
  }
  // ---- layer 1: K=256, heads=4, Nc=256 ----
  {
    dim3 g(256/128, MPAD/128);
    k_gemm_mfma<128,256,4><<<g, 256, 0, stream>>>(Xb, Wt1, Hb, asrc1, adst1, AS1, AD1, 256);
    k_agg<4,true><<<nwaveblk, 256, 0, stream>>>(Hb, AS1, AD1, off, esrc, b1, g1, be1, Xb);
  }
  // ---- layer 2: K=256, heads=1, Nc=64, concat=False ----
  {
    dim3 g(64/64, MPAD/128);
    k_gemm_mfma<64,256,1><<<g, 256, 0, stream>>>(Xb, Wt2, Hb, asrc2, adst2, AS2, AD2, 64);
    k_agg<1,false><<<nwaveblk, 256, 0, stream>>>(Hb, AS2, AD2, off, esrc, b2, g2, be2, out);
  }
}